// Round 4
// baseline (152.911 us; speedup 1.0000x reference)
//
#include <hip/hip_runtime.h>
#include <math.h>

#define NPTS 16384
#define DIN 13
#define KNN 8
#define GL 12                 // group-list depth
#define BIGF 1.7014118e38f    // 0x7F000000 — finite sentinel, id bits 0

typedef _Float16 half8 __attribute__((ext_vector_type(8)));
typedef float f32x4 __attribute__((ext_vector_type(4)));
typedef float f32x16 __attribute__((ext_vector_type(16)));

union HU4 { uint4 u; half8 h; };

__device__ __forceinline__ float silu(float v) {
    return v / (1.0f + __expf(-v));
}

#define MED3(v, a, b) __builtin_amdgcn_fmed3f((v), (a), (b))

#define INS8V(v) {                      \
    d7 = MED3((v), d6, d7);             \
    d6 = MED3((v), d5, d6);             \
    d5 = MED3((v), d4, d5);             \
    d4 = MED3((v), d3, d4);             \
    d3 = MED3((v), d2, d3);             \
    d2 = MED3((v), d1, d2);             \
    d1 = MED3((v), d0, d1);             \
    d0 = fminf((v), d0); }

#define INS12G(v) {                     \
    g11 = MED3((v), g10, g11);          \
    g10 = MED3((v), g9, g10);           \
    g9  = MED3((v), g8, g9);            \
    g8  = MED3((v), g7, g8);            \
    g7  = MED3((v), g6, g7);            \
    g6  = MED3((v), g5, g6);            \
    g5  = MED3((v), g4, g5);            \
    g4  = MED3((v), g3, g4);            \
    g3  = MED3((v), g2, g3);            \
    g2  = MED3((v), g1, g2);            \
    g1  = MED3((v), g0, g1);            \
    g0  = fminf((v), g0); }

#define CSW(p, q) { float lo_ = fminf(m##p, m##q); float hi_ = fmaxf(m##p, m##q); m##p = lo_; m##q = hi_; }

#define CLEAN16() \
    CSW(0,8) CSW(1,9) CSW(2,10) CSW(3,11) CSW(4,12) CSW(5,13) CSW(6,14) CSW(7,15) \
    CSW(0,4) CSW(1,5) CSW(2,6) CSW(3,7) CSW(8,12) CSW(9,13) CSW(10,14) CSW(11,15) \
    CSW(0,2) CSW(1,3) CSW(4,6) CSW(5,7) CSW(8,10) CSW(9,11) CSW(12,14) CSW(13,15) \
    CSW(0,1) CSW(2,3) CSW(4,5) CSW(6,7) CSW(8,9) CSW(10,11) CSW(12,13) CSW(14,15)

#define MERGE12_SHFL(mask) {                                  \
    float b0 = __shfl_xor(g0, (mask), 64);                    \
    float b1 = __shfl_xor(g1, (mask), 64);                    \
    float b2 = __shfl_xor(g2, (mask), 64);                    \
    float b3 = __shfl_xor(g3, (mask), 64);                    \
    float b4 = __shfl_xor(g4, (mask), 64);                    \
    float b5 = __shfl_xor(g5, (mask), 64);                    \
    float b6 = __shfl_xor(g6, (mask), 64);                    \
    float b7 = __shfl_xor(g7, (mask), 64);                    \
    float b8 = __shfl_xor(g8, (mask), 64);                    \
    float b9 = __shfl_xor(g9, (mask), 64);                    \
    float b10 = __shfl_xor(g10, (mask), 64);                  \
    float b11 = __shfl_xor(g11, (mask), 64);                  \
    float m0 = g0, m1 = g1, m2 = g2, m3 = g3;                 \
    float m4 = fminf(g4, b11), m5 = fminf(g5, b10);           \
    float m6 = fminf(g6, b9),  m7 = fminf(g7, b8);            \
    float m8 = fminf(g8, b7),  m9 = fminf(g9, b6);            \
    float m10 = fminf(g10, b5), m11 = fminf(g11, b4);         \
    float m12 = b3, m13 = b2, m14 = b1, m15 = b0;             \
    CLEAN16();                                                \
    g0 = m0; g1 = m1; g2 = m2; g3 = m3; g4 = m4; g5 = m5;     \
    g6 = m6; g7 = m7; g8 = m8; g9 = m9; g10 = m10; g11 = m11; }

#define MERGE12_LDS(LD) {                                     \
    float b0 = LD(0), b1 = LD(1), b2 = LD(2), b3 = LD(3);     \
    float b4 = LD(4), b5 = LD(5), b6 = LD(6), b7 = LD(7);     \
    float b8 = LD(8), b9 = LD(9), b10 = LD(10), b11 = LD(11); \
    float m0 = g0, m1 = g1, m2 = g2, m3 = g3;                 \
    float m4 = fminf(g4, b11), m5 = fminf(g5, b10);           \
    float m6 = fminf(g6, b9),  m7 = fminf(g7, b8);            \
    float m8 = fminf(g8, b7),  m9 = fminf(g9, b6);            \
    float m10 = fminf(g10, b5), m11 = fminf(g11, b4);         \
    float m12 = b3, m13 = b2, m14 = b1, m15 = b0;             \
    CLEAN16();                                                \
    g0 = m0; g1 = m1; g2 = m2; g3 = m3; g4 = m4; g5 = m5;     \
    g6 = m6; g7 = m7; g8 = m8; g9 = m9; g10 = m10; g11 = m11; }

#define MERGE8(mask) {                                   \
    float b0 = __shfl_xor(d0, (mask), 64);               \
    float b1 = __shfl_xor(d1, (mask), 64);               \
    float b2 = __shfl_xor(d2, (mask), 64);               \
    float b3 = __shfl_xor(d3, (mask), 64);               \
    float b4 = __shfl_xor(d4, (mask), 64);               \
    float b5 = __shfl_xor(d5, (mask), 64);               \
    float b6 = __shfl_xor(d6, (mask), 64);               \
    float b7 = __shfl_xor(d7, (mask), 64);               \
    float m0 = fminf(d0, b7), m1 = fminf(d1, b6);        \
    float m2 = fminf(d2, b5), m3 = fminf(d3, b4);        \
    float m4 = fminf(d4, b3), m5 = fminf(d5, b2);        \
    float m6 = fminf(d6, b1), m7 = fminf(d7, b0);        \
    CSW(0,4) CSW(1,5) CSW(2,6) CSW(3,7)                  \
    CSW(0,2) CSW(1,3) CSW(4,6) CSW(5,7)                  \
    CSW(0,1) CSW(2,3) CSW(4,5) CSW(6,7)                  \
    d0 = m0; d1 = m1; d2 = m2; d3 = m3;                  \
    d4 = m4; d5 = m5; d6 = m6; d7 = m7; }

// ---- K1: encoder MLP -> x, H/L/YH/YL f16 splits, SQF, packed SQHL, ACC ----
__global__ __launch_bounds__(64) void k_encoder(
    const float* __restrict__ x_pfc,
    const float* __restrict__ W1, const float* __restrict__ b1,
    const float* __restrict__ W2, const float* __restrict__ b2,
    const float* __restrict__ W3, const float* __restrict__ b3,
    const float* __restrict__ We, const float* __restrict__ be,
    float* __restrict__ xo, _Float16* __restrict__ H, _Float16* __restrict__ L,
    _Float16* __restrict__ YH, _Float16* __restrict__ YL,
    float* __restrict__ SQF, unsigned* __restrict__ SQHL,
    float* __restrict__ ACC)
{
    __shared__ float sW1[DIN * 8];
    __shared__ float sb1[8];
    __shared__ float sW2[8 * 16];
    __shared__ float sb2[16];
    __shared__ float sW3[16 * 15];
    __shared__ float sb3[15];
    __shared__ float sWe[16 * 16];
    __shared__ float sbe[16];
    int t = threadIdx.x;
    for (int q = t; q < DIN * 8; q += 64) sW1[q] = W1[q];
    for (int q = t; q < 8; q += 64) sb1[q] = b1[q];
    for (int q = t; q < 8 * 16; q += 64) sW2[q] = W2[q];
    for (int q = t; q < 16; q += 64) sb2[q] = b2[q];
    for (int q = t; q < 16 * 15; q += 64) sW3[q] = W3[q];
    for (int q = t; q < 15; q += 64) sb3[q] = b3[q];
    for (int q = t; q < 16 * 16; q += 64) sWe[q] = We[q];
    for (int q = t; q < 16; q += 64) sbe[q] = be[q];
    __syncthreads();

    int i = blockIdx.x * 64 + t;
    float in[DIN];
#pragma unroll
    for (int d = 0; d < DIN; ++d) in[d] = x_pfc[i * DIN + d];

    float a1[8];
#pragma unroll
    for (int h = 0; h < 8; ++h) a1[h] = sb1[h];
#pragma unroll
    for (int d = 0; d < DIN; ++d) {
        float v = in[d];
#pragma unroll
        for (int h = 0; h < 8; ++h) a1[h] += v * sW1[d * 8 + h];
    }
#pragma unroll
    for (int h = 0; h < 8; ++h) a1[h] = silu(a1[h]);

    float a2[16];
#pragma unroll
    for (int h = 0; h < 16; ++h) a2[h] = sb2[h];
#pragma unroll
    for (int d = 0; d < 8; ++d) {
        float v = a1[d];
#pragma unroll
        for (int h = 0; h < 16; ++h) a2[h] += v * sW2[d * 16 + h];
    }
#pragma unroll
    for (int h = 0; h < 16; ++h) a2[h] = silu(a2[h]);

    float a3[15];
#pragma unroll
    for (int h = 0; h < 15; ++h) a3[h] = sb3[h];
#pragma unroll
    for (int d = 0; d < 16; ++d) {
        float v = a2[d];
#pragma unroll
        for (int h = 0; h < 15; ++h) a3[h] += v * sW3[d * 15 + h];
    }

    float xr[16];
#pragma unroll
    for (int h = 0; h < 15; ++h) xr[h] = a3[h];
    xr[15] = in[DIN - 1];

    float s = 0.0f;
#pragma unroll
    for (int d = 0; d < 16; ++d) s += xr[d] * xr[d];

    float accb[16];
#pragma unroll
    for (int h = 0; h < 16; ++h) accb[h] = sbe[h];
#pragma unroll
    for (int d = 0; d < 16; ++d) {
        float v = xr[d];
#pragma unroll
        for (int h = 0; h < 16; ++h) accb[h] += v * sWe[d * 16 + h];
    }

    _Float16 hb[16], lb[16], yhb[16], ylb[16];
#pragma unroll
    for (int d = 0; d < 16; ++d) {
        _Float16 h = (_Float16)xr[d];
        hb[d] = h;
        lb[d] = (_Float16)(xr[d] - (float)h);
        float y = -2.0f * xr[d];
        _Float16 yh = (_Float16)y;
        yhb[d] = yh;
        ylb[d] = (_Float16)(y - (float)yh);
    }
    {
        uint4* p;
        p = (uint4*)(H + (size_t)i * 16);  p[0] = ((uint4*)hb)[0];  p[1] = ((uint4*)hb)[1];
        p = (uint4*)(L + (size_t)i * 16);  p[0] = ((uint4*)lb)[0];  p[1] = ((uint4*)lb)[1];
        p = (uint4*)(YH + (size_t)i * 16); p[0] = ((uint4*)yhb)[0]; p[1] = ((uint4*)yhb)[1];
        p = (uint4*)(YL + (size_t)i * 16); p[0] = ((uint4*)ylb)[0]; p[1] = ((uint4*)ylb)[1];
        f32x4* xq = (f32x4*)(xo + (size_t)i * 16);
        f32x4* aq = (f32x4*)(ACC + (size_t)i * 16);
#pragma unroll
        for (int q = 0; q < 4; ++q) {
            f32x4 xv, av;
#pragma unroll
            for (int r = 0; r < 4; ++r) { xv[r] = xr[q * 4 + r]; av[r] = accb[q * 4 + r]; }
            xq[q] = xv;
            aq[q] = av;
        }
    }
    SQF[i] = s;
    {
        // packed f16 hi/lo split of sq: low16 = sqh, high16 = sql
        _Float16 sh = (_Float16)s;
        _Float16 sl = (_Float16)(s - (float)sh);
        unsigned uh = *(const unsigned short*)&sh;
        unsigned ul = *(const unsigned short*)&sl;
        SQHL[i] = (ul << 16) | uh;
    }
}

// ---- K2: MFMA 32x32 KNN ----
// Round-16: sq folded via LDS instead of MFMA. Stage the j-half's SQF
// (8192 f32 = 32KB) in LDS once per block; per tile, init the f32x16
// accumulator directly with 4 broadcast ds_read_b128 (rows (reg&3)+
// 8*(reg>>2)+4*hh are 4 contiguous f32x4 runs). Kills per tile:
//  - the A4.B4 sq-MFMA (4 -> 3 MFMA: pipe floor 32.8K -> 24.6K cyc/SIMD)
//  - the 16 v_mov zero-init of c (ds_reads land in the acc regs)
//  - the squ load + mask/build (2 VALU + 1 vmem)
// Chunked loop (outer x8, inner unroll x4) keeps global offsets <=1536
// halfs (imm-encodable) -> 1 pointer bump per chunk instead of 64-bit
// adds per tile. sq stage ALIASES the merge-tree buffer (sq dead after
// the loop; extra __syncthreads before first STORE12). LDS=32KB, VGPR
// stays <=64 -> 4 blocks/CU residency preserved.
__global__ __launch_bounds__(512, 4) void k_knn(
    const _Float16* __restrict__ H, const _Float16* __restrict__ L,
    const _Float16* __restrict__ YH, const _Float16* __restrict__ YL,
    const float* __restrict__ SQF, unsigned* __restrict__ CV)
{
    __shared__ float sBuf[8192];   // loop: f32 sq of j-half; after: merge tree

    int t = threadIdx.x;
    int w = t >> 6;
    int lane = t & 63;
    int r31 = lane & 31;
    int hh = lane >> 5;
    int ih = blockIdx.x >> 1;
    int jh = blockIdx.x & 1;
    int i0 = ih * 32;

    int gi = i0 + r31;
    half8 B1 = *(const half8*)(YH + (size_t)gi * 16 + hh * 8);
    half8 B2 = *(const half8*)(YL + (size_t)gi * 16 + hh * 8);

    // stage sq (f32) for this block's j-half: 2048 x f32x4, coalesced
    {
        const f32x4* src = (const f32x4*)(SQF + jh * 8192);
        f32x4* dst = (f32x4*)sBuf;
        for (int q = t; q < 2048; q += 512) dst[q] = src[q];
    }

    float g0 = BIGF, g1 = BIGF, g2 = BIGF, g3 = BIGF;
    float g4 = BIGF, g5 = BIGF, g6 = BIGF, g7 = BIGF;
    float g8 = BIGF, g9 = BIGF, g10 = BIGF, g11 = BIGF;

    int jw = jh * 8192 + w * 1024;
    const _Float16* pH = H + ((size_t)(jw + r31)) * 16 + hh * 8;
    const _Float16* pL = L + ((size_t)(jw + r31)) * 16 + hh * 8;
    const float* sqb = sBuf + w * 1024 + hh * 4;
    unsigned idt = (unsigned)((w << 1) | hh);

    __syncthreads();   // sq staged

#pragma unroll 1
    for (int cc = 0; cc < 8; ++cc) {
        // 4-tile load batch (imm offsets 0..1536 halfs = 0..3072B)
        half8 Ah0 = *(const half8*)(pH);
        half8 Al0 = *(const half8*)(pL);
        half8 Ah1 = *(const half8*)(pH + 512);
        half8 Al1 = *(const half8*)(pL + 512);
        half8 Ah2 = *(const half8*)(pH + 1024);
        half8 Al2 = *(const half8*)(pL + 1024);
        half8 Ah3 = *(const half8*)(pH + 1536);
        half8 Al3 = *(const half8*)(pL + 1536);
        const float* sq4 = sqb + cc * 128;
        unsigned idc = idt + (unsigned)(cc << 6);

#define TILE(AH, AL, U) {                                                    \
        const f32x4* s_ = (const f32x4*)(sq4 + (U) * 32);                    \
        f32x4 s0 = s_[0], s1 = s_[2], s2 = s_[4], s3 = s_[6];                \
        f32x16 c;                                                            \
        c[0] = s0[0]; c[1] = s0[1]; c[2] = s0[2]; c[3] = s0[3];              \
        c[4] = s1[0]; c[5] = s1[1]; c[6] = s1[2]; c[7] = s1[3];              \
        c[8] = s2[0]; c[9] = s2[1]; c[10] = s2[2]; c[11] = s2[3];            \
        c[12] = s3[0]; c[13] = s3[1]; c[14] = s3[2]; c[15] = s3[3];          \
        c = __builtin_amdgcn_mfma_f32_32x32x16_f16(AH, B1, c, 0, 0, 0);      \
        c = __builtin_amdgcn_mfma_f32_32x32x16_f16(AL, B1, c, 0, 0, 0);      \
        c = __builtin_amdgcn_mfma_f32_32x32x16_f16(AH, B2, c, 0, 0, 0);      \
        float v0 = fminf(fminf(c[0], c[1]), c[2]);                           \
        float v1 = fminf(fminf(c[3], c[4]), c[5]);                           \
        float v2 = fminf(fminf(c[6], c[7]), c[8]);                           \
        float v3 = fminf(fminf(c[9], c[10]), c[11]);                         \
        float v4 = fminf(fminf(c[12], c[13]), c[14]);                        \
        float v5 = fminf(fminf(v0, v1), c[15]);                              \
        float v6 = fminf(fminf(v2, v3), v4);                                 \
        float vmin = fminf(v5, v6);                                          \
        unsigned pk = (__float_as_uint(vmin) & 0xFFFFFC00u)                  \
                    | (idc + (unsigned)((U) << 4));                          \
        float pf = __uint_as_float(pk);                                      \
        INS12G(pf); }

        TILE(Ah0, Al0, 0)
        TILE(Ah1, Al1, 1)
        TILE(Ah2, Al2, 2)
        TILE(Ah3, Al3, 3)
#undef TILE
        pH += 2048;
        pL += 2048;
    }

    MERGE12_SHFL(32);

    __syncthreads();   // sq reads done everywhere; sBuf reusable as merge tree

#define STORE12() if (lane < 32) {                       \
        sBuf[(w * GL + 0) * 32 + r31] = g0;              \
        sBuf[(w * GL + 1) * 32 + r31] = g1;              \
        sBuf[(w * GL + 2) * 32 + r31] = g2;              \
        sBuf[(w * GL + 3) * 32 + r31] = g3;              \
        sBuf[(w * GL + 4) * 32 + r31] = g4;              \
        sBuf[(w * GL + 5) * 32 + r31] = g5;              \
        sBuf[(w * GL + 6) * 32 + r31] = g6;              \
        sBuf[(w * GL + 7) * 32 + r31] = g7;              \
        sBuf[(w * GL + 8) * 32 + r31] = g8;              \
        sBuf[(w * GL + 9) * 32 + r31] = g9;              \
        sBuf[(w * GL + 10) * 32 + r31] = g10;            \
        sBuf[(w * GL + 11) * 32 + r31] = g11; }

    if (w >= 4) STORE12();
    __syncthreads();
    if (w < 4) {
        int pw = w + 4;
#define LD(s) sBuf[(pw * GL + (s)) * 32 + r31]
        MERGE12_LDS(LD);
#undef LD
    }
    __syncthreads();
    if (w == 2 || w == 3) STORE12();
    __syncthreads();
    if (w < 2) {
        int pw = w + 2;
#define LD(s) sBuf[(pw * GL + (s)) * 32 + r31]
        MERGE12_LDS(LD);
#undef LD
    }
    __syncthreads();
    if (w == 1) STORE12();
    __syncthreads();
    if (w == 0) {
        int pw = 1;
#define LD(s) sBuf[(pw * GL + (s)) * 32 + r31]
        MERGE12_LDS(LD);
#undef LD
        if (lane < 32) {
            unsigned jb = ((unsigned)jh) << 9;
            size_t base = ((size_t)jh * NPTS + (i0 + r31)) * GL;
            CV[base + 0] = __float_as_uint(g0) | jb;
            CV[base + 1] = __float_as_uint(g1) | jb;
            CV[base + 2] = __float_as_uint(g2) | jb;
            CV[base + 3] = __float_as_uint(g3) | jb;
            CV[base + 4] = __float_as_uint(g4) | jb;
            CV[base + 5] = __float_as_uint(g5) | jb;
            CV[base + 6] = __float_as_uint(g6) | jb;
            CV[base + 7] = __float_as_uint(g7) | jb;
            CV[base + 8] = __float_as_uint(g8) | jb;
            CV[base + 9] = __float_as_uint(g9) | jb;
            CV[base + 10] = __float_as_uint(g10) | jb;
            CV[base + 11] = __float_as_uint(g11) | jb;
        }
    }
#undef STORE12
}

// ---- K3: group re-eval + exact top-8 + edge conv + head MLP ----
// (unchanged from round 15 — scratch-free epilogue, 16 lanes/point)
__global__ __launch_bounds__(512, 4) void k_head(
    const float* __restrict__ x, const unsigned* __restrict__ CV,
    const float* __restrict__ SQF,
    const float* __restrict__ x_pfc, const float* __restrict__ ACC,
    const float* __restrict__ We,
    const float* __restrict__ Wf1, const float* __restrict__ bf1,
    const float* __restrict__ Wf2, const float* __restrict__ bf2,
    float* __restrict__ out)
{
    __shared__ float sWe2[16 * 16];
    __shared__ float sWf1[16 * 32];
    __shared__ float sbf1[32];
    __shared__ float sWf2[32 * 16];
    __shared__ float sbf2[16];
    __shared__ int sGrp[32][GL];       // pre-decoded jb bases
    __shared__ int cnt[32];
    __shared__ int sIdx[32 * 8];
    __shared__ float sF1[32 * 33];     // f1 stage, stride 33 (conflict-free)
    int t = threadIdx.x;
    for (int q = t; q < 16 * 16; q += 512) sWe2[q] = We[256 + q];
    for (int q = t; q < 16 * 32; q += 512) sWf1[q] = Wf1[q];
    for (int q = t; q < 32; q += 512) sbf1[q] = bf1[q];
    for (int q = t; q < 32 * 16; q += 512) sWf2[q] = Wf2[q];
    for (int q = t; q < 16; q += 512) sbf2[q] = bf2[q];

    int i0 = blockIdx.x * 32;

    // preamble: 2 threads/point merge the two sorted CV half-lists (wave 0)
    if (t < 64) {
        int pi = t & 31;
        int hf = t >> 5;
        const f32x4* c = (const f32x4*)(CV + ((size_t)hf * NPTS + (i0 + pi)) * GL);
        f32x4 c0 = c[0], c1 = c[1], c2 = c[2];
        float g0 = c0[0], g1 = c0[1], g2 = c0[2], g3 = c0[3];
        float g4 = c1[0], g5 = c1[1], g6 = c1[2], g7 = c1[3];
        float g8 = c2[0], g9 = c2[1], g10 = c2[2], g11 = c2[3];
        MERGE12_SHFL(32);
        if (t < 32) {
            cnt[pi] = 0;
#define DECJB(gk, s) { unsigned id_ = __float_as_uint(gk) & 0x3FFu;          \
            sGrp[pi][s] = (int)(((id_ >> 9) & 1) * 8192 + ((id_ >> 1) & 7) * 1024 + \
                                ((id_ >> 4) & 31) * 32 + (id_ & 1) * 4); }
            DECJB(g0, 0) DECJB(g1, 1) DECJB(g2, 2) DECJB(g3, 3)
            DECJB(g4, 4) DECJB(g5, 5) DECJB(g6, 6) DECJB(g7, 7)
            DECJB(g8, 8) DECJB(g9, 9) DECJB(g10, 10) DECJB(g11, 11)
#undef DECJB
        }
    }
    __syncthreads();

    int l = t & 15;          // lane within point
    int pt = t >> 4;         // point within block (0..31)
    int ql = l & 3;          // quarter within row
    int qd = l >> 2;         // row within run
    int i = i0 + pt;

    float xi[16];
    {
        const f32x4* xiv = (const f32x4*)(x + (size_t)i * 16);
#pragma unroll
        for (int q = 0; q < 4; ++q) {
            f32x4 a = xiv[q];
#pragma unroll
            for (int r = 0; r < 4; ++r) xi[q * 4 + r] = a[r];
        }
    }
    // this lane's quarter of xi (runtime ql -> memory load, not reg idx)
    f32x4 xiq = ((const f32x4*)(x + (size_t)i * 16))[ql];

    // scan A: 12 groups x 4 coalesced runs; per-lane top-8 over owned vals
    float val[12];
    float d0 = BIGF, d1 = BIGF, d2 = BIGF, d3 = BIGF;
    float d4 = BIGF, d5 = BIGF, d6 = BIGF, d7 = BIGF;
#pragma unroll
    for (int g = 0; g < GL; ++g) {
        int jb = sGrp[pt][g];
        float vg = BIGF;
#pragma unroll
        for (int rho = 0; rho < 4; ++rho) {
            // run of 4 rows (256B) at jb+rho*8: lane l takes 16B at +l*16
            f32x4 a = *((const f32x4*)(x + ((size_t)(jb + rho * 8)) * 16) + l);
            float qdot = xiq[0] * a[0];
            qdot = fmaf(xiq[1], a[1], qdot);
            qdot = fmaf(xiq[2], a[2], qdot);
            qdot = fmaf(xiq[3], a[3], qdot);
            qdot += __shfl_xor(qdot, 1, 64);
            qdot += __shfl_xor(qdot, 2, 64);
            float v = fmaf(qdot, -2.0f, SQF[jb + rho * 8 + qd]);
            vg = (ql == rho) ? v : vg;   // owner keeps candidate (rho==ql, qd)
        }
        val[g] = vg;
        INS8V(vg);
    }

    // exact kth over the point's 192 candidates (16-lane butterfly)
    MERGE8(1);
    MERGE8(2);
    MERGE8(4);
    MERGE8(8);
    float kth = d7;

    // scan B: register re-scan, collect ids
#pragma unroll
    for (int g = 0; g < GL; ++g) {
        float v = val[g];
        if (v <= kth) {
            int j = sGrp[pt][g] + ql * 8 + qd;
            int p = atomicAdd(&cnt[pt], 1);
            if (p < KNN) sIdx[pt * 8 + p] = j;
        }
    }
    __syncthreads();

    int e8 = l & 7;
    int j = sIdx[pt * 8 + e8];

    float xd[16];
    {
        const f32x4* xjv = (const f32x4*)(x + (size_t)j * 16);
#pragma unroll
        for (int q = 0; q < 4; ++q) {
            f32x4 a = xjv[q];
#pragma unroll
            for (int r = 0; r < 4; ++r) xd[q * 4 + r] = a[r] - xi[q * 4 + r];
        }
    }

    float acc[16];
    {
        const f32x4* av = (const f32x4*)(ACC + (size_t)i * 16);
#pragma unroll
        for (int q = 0; q < 4; ++q) {
            f32x4 a = av[q];
#pragma unroll
            for (int r = 0; r < 4; ++r) acc[q * 4 + r] = a[r];
        }
    }
#pragma unroll
    for (int d = 0; d < 16; ++d) {
        float v = xd[d];
#pragma unroll
        for (int h = 0; h < 16; ++h) acc[h] += v * sWe2[d * 16 + h];
    }

    float feats[16];
#pragma unroll
    for (int h = 0; h < 16; ++h) feats[h] = silu(acc[h]);

    // mean over 8 edges (lanes 8..15 hold duplicate msgs -> same mean;
    // feats identical across all 16 lanes of the point afterwards)
#pragma unroll
    for (int mask = 1; mask <= 4; mask <<= 1) {
#pragma unroll
        for (int h = 0; h < 16; ++h) feats[h] += __shfl_xor(feats[h], mask, 64);
    }
#pragma unroll
    for (int h = 0; h < 16; ++h) feats[h] *= 0.125f;

    // f1: lane l computes outputs l and l+16 (Wf1 reads broadcast per k)
    float p0 = sbf1[l];
    float p1 = sbf1[l + 16];
#pragma unroll
    for (int k = 0; k < 16; ++k) {
        float v = feats[k];
        p0 = fmaf(v, sWf1[k * 32 + l], p0);
        p1 = fmaf(v, sWf1[k * 32 + l + 16], p1);
    }
    p0 = silu(p0);
    p1 = silu(p1);
    sF1[pt * 33 + l] = p0;
    sF1[pt * 33 + 16 + l] = p1;
    __syncthreads();

    // f2: lane l computes output l; sF1 reads are 4-bank-spread broadcast
    float o = sbf2[l];
#pragma unroll
    for (int k = 0; k < 32; ++k)
        o = fmaf(sF1[pt * 33 + k], sWf2[k * 16 + l], o);

    out[(size_t)i * 29 + l] = o;
    if (l < DIN) out[(size_t)i * 29 + 16 + l] = x_pfc[i * DIN + l];
}

extern "C" void kernel_launch(void* const* d_in, const int* in_sizes, int n_in,
                              void* d_out, int out_size, void* d_ws, size_t ws_size,
                              hipStream_t stream)
{
    const float* x_pfc = (const float*)d_in[0];
    const float* W1 = (const float*)d_in[1];
    const float* b1 = (const float*)d_in[2];
    const float* W2 = (const float*)d_in[3];
    const float* b2 = (const float*)d_in[4];
    const float* W3 = (const float*)d_in[5];
    const float* b3 = (const float*)d_in[6];
    const float* We = (const float*)d_in[7];
    const float* be = (const float*)d_in[8];
    const float* Wf1 = (const float*)d_in[9];
    const float* bf1 = (const float*)d_in[10];
    const float* Wf2 = (const float*)d_in[11];
    const float* bf2 = (const float*)d_in[12];
    float* out = (float*)d_out;

    float* xw = (float*)d_ws;                         // N*16 f32
    float* ACCa = xw + (size_t)NPTS * 16;             // N*16 f32
    _Float16* Ha = (_Float16*)(ACCa + (size_t)NPTS * 16);  // N*16 f16
    _Float16* La = Ha + (size_t)NPTS * 16;
    _Float16* YHa = La + (size_t)NPTS * 16;
    _Float16* YLa = YHa + (size_t)NPTS * 16;
    float* SQFa = (float*)(YLa + (size_t)NPTS * 16);  // N f32
    unsigned* SQHLa = (unsigned*)(SQFa + NPTS);       // N u32 (packed f16 split)
    unsigned* CVa = SQHLa + NPTS;                     // 2*N*GL u32

    hipLaunchKernelGGL(k_encoder, dim3(NPTS / 64), dim3(64), 0, stream,
                       x_pfc, W1, b1, W2, b2, W3, b3, We, be,
                       xw, Ha, La, YHa, YLa, SQFa, SQHLa, ACCa);
    hipLaunchKernelGGL(k_knn, dim3(NPTS / 32 * 2), dim3(512), 0, stream,
                       Ha, La, YHa, YLa, SQFa, CVa);
    hipLaunchKernelGGL(k_head, dim3(NPTS / 32), dim3(512), 0, stream,
                       xw, CVa, SQFa, x_pfc, ACCa, We, Wf1, bf1, Wf2, bf2, out);
}

// Round 6
// 152.146 us; speedup vs baseline: 1.0050x; 1.0050x over previous
//
#include <hip/hip_runtime.h>
#include <math.h>

#define NPTS 16384
#define DIN 13
#define KNN 8
#define GL 12                 // group-list depth
#define BIGF 1.7014118e38f    // 0x7F000000 — finite sentinel, id bits 0

typedef _Float16 half8 __attribute__((ext_vector_type(8)));
typedef float f32x4 __attribute__((ext_vector_type(4)));
typedef float f32x16 __attribute__((ext_vector_type(16)));

union HU4 { uint4 u; half8 h; };
union C16 { f32x16 w; f32x4 q[4]; };

__device__ __forceinline__ float silu(float v) {
    return v / (1.0f + __expf(-v));
}

#define MED3(v, a, b) __builtin_amdgcn_fmed3f((v), (a), (b))

#define INS8V(v) {                      \
    d7 = MED3((v), d6, d7);             \
    d6 = MED3((v), d5, d6);             \
    d5 = MED3((v), d4, d5);             \
    d4 = MED3((v), d3, d4);             \
    d3 = MED3((v), d2, d3);             \
    d2 = MED3((v), d1, d2);             \
    d1 = MED3((v), d0, d1);             \
    d0 = fminf((v), d0); }

#define INS12G(v) {                     \
    g11 = MED3((v), g10, g11);          \
    g10 = MED3((v), g9, g10);           \
    g9  = MED3((v), g8, g9);            \
    g8  = MED3((v), g7, g8);            \
    g7  = MED3((v), g6, g7);            \
    g6  = MED3((v), g5, g6);            \
    g5  = MED3((v), g4, g5);            \
    g4  = MED3((v), g3, g4);            \
    g3  = MED3((v), g2, g3);            \
    g2  = MED3((v), g1, g2);            \
    g1  = MED3((v), g0, g1);            \
    g0  = fminf((v), g0); }

#define CSW(p, q) { float lo_ = fminf(m##p, m##q); float hi_ = fmaxf(m##p, m##q); m##p = lo_; m##q = hi_; }

#define CLEAN16() \
    CSW(0,8) CSW(1,9) CSW(2,10) CSW(3,11) CSW(4,12) CSW(5,13) CSW(6,14) CSW(7,15) \
    CSW(0,4) CSW(1,5) CSW(2,6) CSW(3,7) CSW(8,12) CSW(9,13) CSW(10,14) CSW(11,15) \
    CSW(0,2) CSW(1,3) CSW(4,6) CSW(5,7) CSW(8,10) CSW(9,11) CSW(12,14) CSW(13,15) \
    CSW(0,1) CSW(2,3) CSW(4,5) CSW(6,7) CSW(8,9) CSW(10,11) CSW(12,13) CSW(14,15)

#define MERGE12_SHFL(mask) {                                  \
    float b0 = __shfl_xor(g0, (mask), 64);                    \
    float b1 = __shfl_xor(g1, (mask), 64);                    \
    float b2 = __shfl_xor(g2, (mask), 64);                    \
    float b3 = __shfl_xor(g3, (mask), 64);                    \
    float b4 = __shfl_xor(g4, (mask), 64);                    \
    float b5 = __shfl_xor(g5, (mask), 64);                    \
    float b6 = __shfl_xor(g6, (mask), 64);                    \
    float b7 = __shfl_xor(g7, (mask), 64);                    \
    float b8 = __shfl_xor(g8, (mask), 64);                    \
    float b9 = __shfl_xor(g9, (mask), 64);                    \
    float b10 = __shfl_xor(g10, (mask), 64);                  \
    float b11 = __shfl_xor(g11, (mask), 64);                  \
    float m0 = g0, m1 = g1, m2 = g2, m3 = g3;                 \
    float m4 = fminf(g4, b11), m5 = fminf(g5, b10);           \
    float m6 = fminf(g6, b9),  m7 = fminf(g7, b8);            \
    float m8 = fminf(g8, b7),  m9 = fminf(g9, b6);            \
    float m10 = fminf(g10, b5), m11 = fminf(g11, b4);         \
    float m12 = b3, m13 = b2, m14 = b1, m15 = b0;             \
    CLEAN16();                                                \
    g0 = m0; g1 = m1; g2 = m2; g3 = m3; g4 = m4; g5 = m5;     \
    g6 = m6; g7 = m7; g8 = m8; g9 = m9; g10 = m10; g11 = m11; }

#define MERGE12_LDS(LD) {                                     \
    float b0 = LD(0), b1 = LD(1), b2 = LD(2), b3 = LD(3);     \
    float b4 = LD(4), b5 = LD(5), b6 = LD(6), b7 = LD(7);     \
    float b8 = LD(8), b9 = LD(9), b10 = LD(10), b11 = LD(11); \
    float m0 = g0, m1 = g1, m2 = g2, m3 = g3;                 \
    float m4 = fminf(g4, b11), m5 = fminf(g5, b10);           \
    float m6 = fminf(g6, b9),  m7 = fminf(g7, b8);            \
    float m8 = fminf(g8, b7),  m9 = fminf(g9, b6);            \
    float m10 = fminf(g10, b5), m11 = fminf(g11, b4);         \
    float m12 = b3, m13 = b2, m14 = b1, m15 = b0;             \
    CLEAN16();                                                \
    g0 = m0; g1 = m1; g2 = m2; g3 = m3; g4 = m4; g5 = m5;     \
    g6 = m6; g7 = m7; g8 = m8; g9 = m9; g10 = m10; g11 = m11; }

#define MERGE8(mask) {                                   \
    float b0 = __shfl_xor(d0, (mask), 64);               \
    float b1 = __shfl_xor(d1, (mask), 64);               \
    float b2 = __shfl_xor(d2, (mask), 64);               \
    float b3 = __shfl_xor(d3, (mask), 64);               \
    float b4 = __shfl_xor(d4, (mask), 64);               \
    float b5 = __shfl_xor(d5, (mask), 64);               \
    float b6 = __shfl_xor(d6, (mask), 64);               \
    float b7 = __shfl_xor(d7, (mask), 64);               \
    float m0 = fminf(d0, b7), m1 = fminf(d1, b6);        \
    float m2 = fminf(d2, b5), m3 = fminf(d3, b4);        \
    float m4 = fminf(d4, b3), m5 = fminf(d5, b2);        \
    float m6 = fminf(d6, b1), m7 = fminf(d7, b0);        \
    CSW(0,4) CSW(1,5) CSW(2,6) CSW(3,7)                  \
    CSW(0,2) CSW(1,3) CSW(4,6) CSW(5,7)                  \
    CSW(0,1) CSW(2,3) CSW(4,5) CSW(6,7)                  \
    d0 = m0; d1 = m1; d2 = m2; d3 = m3;                  \
    d4 = m4; d5 = m5; d6 = m6; d7 = m7; }

// ---- K1: encoder MLP -> x, H/L/YH/YL f16 splits, SQF, packed SQHL, ACC ----
__global__ __launch_bounds__(64) void k_encoder(
    const float* __restrict__ x_pfc,
    const float* __restrict__ W1, const float* __restrict__ b1,
    const float* __restrict__ W2, const float* __restrict__ b2,
    const float* __restrict__ W3, const float* __restrict__ b3,
    const float* __restrict__ We, const float* __restrict__ be,
    float* __restrict__ xo, _Float16* __restrict__ H, _Float16* __restrict__ L,
    _Float16* __restrict__ YH, _Float16* __restrict__ YL,
    float* __restrict__ SQF, unsigned* __restrict__ SQHL,
    float* __restrict__ ACC)
{
    __shared__ float sW1[DIN * 8];
    __shared__ float sb1[8];
    __shared__ float sW2[8 * 16];
    __shared__ float sb2[16];
    __shared__ float sW3[16 * 15];
    __shared__ float sb3[15];
    __shared__ float sWe[16 * 16];
    __shared__ float sbe[16];
    int t = threadIdx.x;
    for (int q = t; q < DIN * 8; q += 64) sW1[q] = W1[q];
    for (int q = t; q < 8; q += 64) sb1[q] = b1[q];
    for (int q = t; q < 8 * 16; q += 64) sW2[q] = W2[q];
    for (int q = t; q < 16; q += 64) sb2[q] = b2[q];
    for (int q = t; q < 16 * 15; q += 64) sW3[q] = W3[q];
    for (int q = t; q < 15; q += 64) sb3[q] = b3[q];
    for (int q = t; q < 16 * 16; q += 64) sWe[q] = We[q];
    for (int q = t; q < 16; q += 64) sbe[q] = be[q];
    __syncthreads();

    int i = blockIdx.x * 64 + t;
    float in[DIN];
#pragma unroll
    for (int d = 0; d < DIN; ++d) in[d] = x_pfc[i * DIN + d];

    float a1[8];
#pragma unroll
    for (int h = 0; h < 8; ++h) a1[h] = sb1[h];
#pragma unroll
    for (int d = 0; d < DIN; ++d) {
        float v = in[d];
#pragma unroll
        for (int h = 0; h < 8; ++h) a1[h] += v * sW1[d * 8 + h];
    }
#pragma unroll
    for (int h = 0; h < 8; ++h) a1[h] = silu(a1[h]);

    float a2[16];
#pragma unroll
    for (int h = 0; h < 16; ++h) a2[h] = sb2[h];
#pragma unroll
    for (int d = 0; d < 8; ++d) {
        float v = a1[d];
#pragma unroll
        for (int h = 0; h < 16; ++h) a2[h] += v * sW2[d * 16 + h];
    }
#pragma unroll
    for (int h = 0; h < 16; ++h) a2[h] = silu(a2[h]);

    float a3[15];
#pragma unroll
    for (int h = 0; h < 15; ++h) a3[h] = sb3[h];
#pragma unroll
    for (int d = 0; d < 16; ++d) {
        float v = a2[d];
#pragma unroll
        for (int h = 0; h < 15; ++h) a3[h] += v * sW3[d * 15 + h];
    }

    float xr[16];
#pragma unroll
    for (int h = 0; h < 15; ++h) xr[h] = a3[h];
    xr[15] = in[DIN - 1];

    float s = 0.0f;
#pragma unroll
    for (int d = 0; d < 16; ++d) s += xr[d] * xr[d];

    float accb[16];
#pragma unroll
    for (int h = 0; h < 16; ++h) accb[h] = sbe[h];
#pragma unroll
    for (int d = 0; d < 16; ++d) {
        float v = xr[d];
#pragma unroll
        for (int h = 0; h < 16; ++h) accb[h] += v * sWe[d * 16 + h];
    }

    _Float16 hb[16], lb[16], yhb[16], ylb[16];
#pragma unroll
    for (int d = 0; d < 16; ++d) {
        _Float16 h = (_Float16)xr[d];
        hb[d] = h;
        lb[d] = (_Float16)(xr[d] - (float)h);
        float y = -2.0f * xr[d];
        _Float16 yh = (_Float16)y;
        yhb[d] = yh;
        ylb[d] = (_Float16)(y - (float)yh);
    }
    {
        uint4* p;
        p = (uint4*)(H + (size_t)i * 16);  p[0] = ((uint4*)hb)[0];  p[1] = ((uint4*)hb)[1];
        p = (uint4*)(L + (size_t)i * 16);  p[0] = ((uint4*)lb)[0];  p[1] = ((uint4*)lb)[1];
        p = (uint4*)(YH + (size_t)i * 16); p[0] = ((uint4*)yhb)[0]; p[1] = ((uint4*)yhb)[1];
        p = (uint4*)(YL + (size_t)i * 16); p[0] = ((uint4*)ylb)[0]; p[1] = ((uint4*)ylb)[1];
        f32x4* xq = (f32x4*)(xo + (size_t)i * 16);
        f32x4* aq = (f32x4*)(ACC + (size_t)i * 16);
#pragma unroll
        for (int q = 0; q < 4; ++q) {
            f32x4 xv, av;
#pragma unroll
            for (int r = 0; r < 4; ++r) { xv[r] = xr[q * 4 + r]; av[r] = accb[q * 4 + r]; }
            xq[q] = xv;
            aq[q] = av;
        }
    }
    SQF[i] = s;
    {
        // packed f16 hi/lo split of sq: low16 = sqh, high16 = sql
        _Float16 sh = (_Float16)s;
        _Float16 sl = (_Float16)(s - (float)sh);
        unsigned uh = *(const unsigned short*)&sh;
        unsigned ul = *(const unsigned short*)&sl;
        SQHL[i] = (ul << 16) | uh;
    }
}

// ---- K2: MFMA 32x32 KNN ----
// Round-18 == round-17 resubmit (round-17 bench died on container acquire,
// zero signal). Latency-hiding pass:
//  - explicit register double-buffer: 2-tile chunks, prefetch chunk c+1's
//    4 loads BEFORE computing chunk c (L2 ~200cy hides under ~400cy of
//    MFMA+reduce), 15 steady chunks + epilogue chunk.
//  - accumulator init via union quads (ds_read_b128 lands in acc regs,
//    no 16x v_mov).
//  - launch_bounds(512,6): raise the occupancy floor vs (512,4).
__global__ __launch_bounds__(512, 6) void k_knn(
    const _Float16* __restrict__ H, const _Float16* __restrict__ L,
    const _Float16* __restrict__ YH, const _Float16* __restrict__ YL,
    const float* __restrict__ SQF, unsigned* __restrict__ CV)
{
    __shared__ float sBuf[8192];   // loop: f32 sq of j-half; after: merge tree

    int t = threadIdx.x;
    int w = t >> 6;
    int lane = t & 63;
    int r31 = lane & 31;
    int hh = lane >> 5;
    int ih = blockIdx.x >> 1;
    int jh = blockIdx.x & 1;
    int i0 = ih * 32;

    int gi = i0 + r31;
    half8 B1 = *(const half8*)(YH + (size_t)gi * 16 + hh * 8);
    half8 B2 = *(const half8*)(YL + (size_t)gi * 16 + hh * 8);

    // stage sq (f32) for this block's j-half: 2048 x f32x4, coalesced
    {
        const f32x4* src = (const f32x4*)(SQF + jh * 8192);
        f32x4* dst = (f32x4*)sBuf;
        for (int q = t; q < 2048; q += 512) dst[q] = src[q];
    }

    float g0 = BIGF, g1 = BIGF, g2 = BIGF, g3 = BIGF;
    float g4 = BIGF, g5 = BIGF, g6 = BIGF, g7 = BIGF;
    float g8 = BIGF, g9 = BIGF, g10 = BIGF, g11 = BIGF;

    int jw = jh * 8192 + w * 1024;
    const _Float16* pH = H + ((size_t)(jw + r31)) * 16 + hh * 8;
    const _Float16* pL = L + ((size_t)(jw + r31)) * 16 + hh * 8;
    const float* sqb = sBuf + w * 1024 + hh * 4;
    unsigned idt = (unsigned)((w << 1) | hh);

    __syncthreads();   // sq staged

#define TILE(AH, AL, SQ4, IDC, U) {                                          \
        const f32x4* s_ = (const f32x4*)((SQ4) + (U) * 32);                  \
        C16 c;                                                               \
        c.q[0] = s_[0]; c.q[1] = s_[2]; c.q[2] = s_[4]; c.q[3] = s_[6];      \
        c.w = __builtin_amdgcn_mfma_f32_32x32x16_f16(AH, B1, c.w, 0, 0, 0);  \
        c.w = __builtin_amdgcn_mfma_f32_32x32x16_f16(AL, B1, c.w, 0, 0, 0);  \
        c.w = __builtin_amdgcn_mfma_f32_32x32x16_f16(AH, B2, c.w, 0, 0, 0);  \
        float v0 = fminf(fminf(c.w[0], c.w[1]), c.w[2]);                     \
        float v1 = fminf(fminf(c.w[3], c.w[4]), c.w[5]);                     \
        float v2 = fminf(fminf(c.w[6], c.w[7]), c.w[8]);                     \
        float v3 = fminf(fminf(c.w[9], c.w[10]), c.w[11]);                   \
        float v4 = fminf(fminf(c.w[12], c.w[13]), c.w[14]);                  \
        float v5 = fminf(fminf(v0, v1), c.w[15]);                            \
        float v6 = fminf(fminf(v2, v3), v4);                                 \
        float vmin = fminf(v5, v6);                                          \
        unsigned pk = (__float_as_uint(vmin) & 0xFFFFFC00u)                  \
                    | ((IDC) + (unsigned)((U) << 4));                        \
        float pf = __uint_as_float(pk);                                      \
        INS12G(pf); }

    // prologue: load chunk 0 (tiles 0,1)
    half8 cAh0 = *(const half8*)(pH);
    half8 cAl0 = *(const half8*)(pL);
    half8 cAh1 = *(const half8*)(pH + 512);
    half8 cAl1 = *(const half8*)(pL + 512);

#pragma unroll 1
    for (int cc = 0; cc < 15; ++cc) {
        // prefetch chunk cc+1 (tiles 2cc+2, 2cc+3)
        half8 nAh0 = *(const half8*)(pH + 1024);
        half8 nAl0 = *(const half8*)(pL + 1024);
        half8 nAh1 = *(const half8*)(pH + 1536);
        half8 nAl1 = *(const half8*)(pL + 1536);

        const float* sq4 = sqb + cc * 64;
        unsigned idc = idt + (unsigned)(cc << 5);
        TILE(cAh0, cAl0, sq4, idc, 0)
        TILE(cAh1, cAl1, sq4, idc, 1)

        cAh0 = nAh0; cAl0 = nAl0; cAh1 = nAh1; cAl1 = nAl1;
        pH += 1024;
        pL += 1024;
    }
    {   // epilogue chunk (tiles 30,31) — no prefetch
        const float* sq4 = sqb + 15 * 64;
        unsigned idc = idt + (unsigned)(15 << 5);
        TILE(cAh0, cAl0, sq4, idc, 0)
        TILE(cAh1, cAl1, sq4, idc, 1)
    }
#undef TILE

    MERGE12_SHFL(32);

    __syncthreads();   // sq reads done everywhere; sBuf reusable as merge tree

#define STORE12() if (lane < 32) {                       \
        sBuf[(w * GL + 0) * 32 + r31] = g0;              \
        sBuf[(w * GL + 1) * 32 + r31] = g1;              \
        sBuf[(w * GL + 2) * 32 + r31] = g2;              \
        sBuf[(w * GL + 3) * 32 + r31] = g3;              \
        sBuf[(w * GL + 4) * 32 + r31] = g4;              \
        sBuf[(w * GL + 5) * 32 + r31] = g5;              \
        sBuf[(w * GL + 6) * 32 + r31] = g6;              \
        sBuf[(w * GL + 7) * 32 + r31] = g7;              \
        sBuf[(w * GL + 8) * 32 + r31] = g8;              \
        sBuf[(w * GL + 9) * 32 + r31] = g9;              \
        sBuf[(w * GL + 10) * 32 + r31] = g10;            \
        sBuf[(w * GL + 11) * 32 + r31] = g11; }

    if (w >= 4) STORE12();
    __syncthreads();
    if (w < 4) {
        int pw = w + 4;
#define LD(s) sBuf[(pw * GL + (s)) * 32 + r31]
        MERGE12_LDS(LD);
#undef LD
    }
    __syncthreads();
    if (w == 2 || w == 3) STORE12();
    __syncthreads();
    if (w < 2) {
        int pw = w + 2;
#define LD(s) sBuf[(pw * GL + (s)) * 32 + r31]
        MERGE12_LDS(LD);
#undef LD
    }
    __syncthreads();
    if (w == 1) STORE12();
    __syncthreads();
    if (w == 0) {
        int pw = 1;
#define LD(s) sBuf[(pw * GL + (s)) * 32 + r31]
        MERGE12_LDS(LD);
#undef LD
        if (lane < 32) {
            unsigned jb = ((unsigned)jh) << 9;
            size_t base = ((size_t)jh * NPTS + (i0 + r31)) * GL;
            CV[base + 0] = __float_as_uint(g0) | jb;
            CV[base + 1] = __float_as_uint(g1) | jb;
            CV[base + 2] = __float_as_uint(g2) | jb;
            CV[base + 3] = __float_as_uint(g3) | jb;
            CV[base + 4] = __float_as_uint(g4) | jb;
            CV[base + 5] = __float_as_uint(g5) | jb;
            CV[base + 6] = __float_as_uint(g6) | jb;
            CV[base + 7] = __float_as_uint(g7) | jb;
            CV[base + 8] = __float_as_uint(g8) | jb;
            CV[base + 9] = __float_as_uint(g9) | jb;
            CV[base + 10] = __float_as_uint(g10) | jb;
            CV[base + 11] = __float_as_uint(g11) | jb;
        }
    }
#undef STORE12
}

// ---- K3: group re-eval + exact top-8 + edge conv + head MLP ----
// (unchanged from round 15 — scratch-free epilogue, 16 lanes/point)
__global__ __launch_bounds__(512, 4) void k_head(
    const float* __restrict__ x, const unsigned* __restrict__ CV,
    const float* __restrict__ SQF,
    const float* __restrict__ x_pfc, const float* __restrict__ ACC,
    const float* __restrict__ We,
    const float* __restrict__ Wf1, const float* __restrict__ bf1,
    const float* __restrict__ Wf2, const float* __restrict__ bf2,
    float* __restrict__ out)
{
    __shared__ float sWe2[16 * 16];
    __shared__ float sWf1[16 * 32];
    __shared__ float sbf1[32];
    __shared__ float sWf2[32 * 16];
    __shared__ float sbf2[16];
    __shared__ int sGrp[32][GL];       // pre-decoded jb bases
    __shared__ int cnt[32];
    __shared__ int sIdx[32 * 8];
    __shared__ float sF1[32 * 33];     // f1 stage, stride 33 (conflict-free)
    int t = threadIdx.x;
    for (int q = t; q < 16 * 16; q += 512) sWe2[q] = We[256 + q];
    for (int q = t; q < 16 * 32; q += 512) sWf1[q] = Wf1[q];
    for (int q = t; q < 32; q += 512) sbf1[q] = bf1[q];
    for (int q = t; q < 32 * 16; q += 512) sWf2[q] = Wf2[q];
    for (int q = t; q < 16; q += 512) sbf2[q] = bf2[q];

    int i0 = blockIdx.x * 32;

    // preamble: 2 threads/point merge the two sorted CV half-lists (wave 0)
    if (t < 64) {
        int pi = t & 31;
        int hf = t >> 5;
        const f32x4* c = (const f32x4*)(CV + ((size_t)hf * NPTS + (i0 + pi)) * GL);
        f32x4 c0 = c[0], c1 = c[1], c2 = c[2];
        float g0 = c0[0], g1 = c0[1], g2 = c0[2], g3 = c0[3];
        float g4 = c1[0], g5 = c1[1], g6 = c1[2], g7 = c1[3];
        float g8 = c2[0], g9 = c2[1], g10 = c2[2], g11 = c2[3];
        MERGE12_SHFL(32);
        if (t < 32) {
            cnt[pi] = 0;
#define DECJB(gk, s) { unsigned id_ = __float_as_uint(gk) & 0x3FFu;          \
            sGrp[pi][s] = (int)(((id_ >> 9) & 1) * 8192 + ((id_ >> 1) & 7) * 1024 + \
                                ((id_ >> 4) & 31) * 32 + (id_ & 1) * 4); }
            DECJB(g0, 0) DECJB(g1, 1) DECJB(g2, 2) DECJB(g3, 3)
            DECJB(g4, 4) DECJB(g5, 5) DECJB(g6, 6) DECJB(g7, 7)
            DECJB(g8, 8) DECJB(g9, 9) DECJB(g10, 10) DECJB(g11, 11)
#undef DECJB
        }
    }
    __syncthreads();

    int l = t & 15;          // lane within point
    int pt = t >> 4;         // point within block (0..31)
    int ql = l & 3;          // quarter within row
    int qd = l >> 2;         // row within run
    int i = i0 + pt;

    float xi[16];
    {
        const f32x4* xiv = (const f32x4*)(x + (size_t)i * 16);
#pragma unroll
        for (int q = 0; q < 4; ++q) {
            f32x4 a = xiv[q];
#pragma unroll
            for (int r = 0; r < 4; ++r) xi[q * 4 + r] = a[r];
        }
    }
    // this lane's quarter of xi (runtime ql -> memory load, not reg idx)
    f32x4 xiq = ((const f32x4*)(x + (size_t)i * 16))[ql];

    // scan A: 12 groups x 4 coalesced runs; per-lane top-8 over owned vals
    float val[12];
    float d0 = BIGF, d1 = BIGF, d2 = BIGF, d3 = BIGF;
    float d4 = BIGF, d5 = BIGF, d6 = BIGF, d7 = BIGF;
#pragma unroll
    for (int g = 0; g < GL; ++g) {
        int jb = sGrp[pt][g];
        float vg = BIGF;
#pragma unroll
        for (int rho = 0; rho < 4; ++rho) {
            // run of 4 rows (256B) at jb+rho*8: lane l takes 16B at +l*16
            f32x4 a = *((const f32x4*)(x + ((size_t)(jb + rho * 8)) * 16) + l);
            float qdot = xiq[0] * a[0];
            qdot = fmaf(xiq[1], a[1], qdot);
            qdot = fmaf(xiq[2], a[2], qdot);
            qdot = fmaf(xiq[3], a[3], qdot);
            qdot += __shfl_xor(qdot, 1, 64);
            qdot += __shfl_xor(qdot, 2, 64);
            float v = fmaf(qdot, -2.0f, SQF[jb + rho * 8 + qd]);
            vg = (ql == rho) ? v : vg;   // owner keeps candidate (rho==ql, qd)
        }
        val[g] = vg;
        INS8V(vg);
    }

    // exact kth over the point's 192 candidates (16-lane butterfly)
    MERGE8(1);
    MERGE8(2);
    MERGE8(4);
    MERGE8(8);
    float kth = d7;

    // scan B: register re-scan, collect ids
#pragma unroll
    for (int g = 0; g < GL; ++g) {
        float v = val[g];
        if (v <= kth) {
            int j = sGrp[pt][g] + ql * 8 + qd;
            int p = atomicAdd(&cnt[pt], 1);
            if (p < KNN) sIdx[pt * 8 + p] = j;
        }
    }
    __syncthreads();

    int e8 = l & 7;
    int j = sIdx[pt * 8 + e8];

    float xd[16];
    {
        const f32x4* xjv = (const f32x4*)(x + (size_t)j * 16);
#pragma unroll
        for (int q = 0; q < 4; ++q) {
            f32x4 a = xjv[q];
#pragma unroll
            for (int r = 0; r < 4; ++r) xd[q * 4 + r] = a[r] - xi[q * 4 + r];
        }
    }

    float acc[16];
    {
        const f32x4* av = (const f32x4*)(ACC + (size_t)i * 16);
#pragma unroll
        for (int q = 0; q < 4; ++q) {
            f32x4 a = av[q];
#pragma unroll
            for (int r = 0; r < 4; ++r) acc[q * 4 + r] = a[r];
        }
    }
#pragma unroll
    for (int d = 0; d < 16; ++d) {
        float v = xd[d];
#pragma unroll
        for (int h = 0; h < 16; ++h) acc[h] += v * sWe2[d * 16 + h];
    }

    float feats[16];
#pragma unroll
    for (int h = 0; h < 16; ++h) feats[h] = silu(acc[h]);

    // mean over 8 edges (lanes 8..15 hold duplicate msgs -> same mean;
    // feats identical across all 16 lanes of the point afterwards)
#pragma unroll
    for (int mask = 1; mask <= 4; mask <<= 1) {
#pragma unroll
        for (int h = 0; h < 16; ++h) feats[h] += __shfl_xor(feats[h], mask, 64);
    }
#pragma unroll
    for (int h = 0; h < 16; ++h) feats[h] *= 0.125f;

    // f1: lane l computes outputs l and l+16 (Wf1 reads broadcast per k)
    float p0 = sbf1[l];
    float p1 = sbf1[l + 16];
#pragma unroll
    for (int k = 0; k < 16; ++k) {
        float v = feats[k];
        p0 = fmaf(v, sWf1[k * 32 + l], p0);
        p1 = fmaf(v, sWf1[k * 32 + l + 16], p1);
    }
    p0 = silu(p0);
    p1 = silu(p1);
    sF1[pt * 33 + l] = p0;
    sF1[pt * 33 + 16 + l] = p1;
    __syncthreads();

    // f2: lane l computes output l; sF1 reads are 4-bank-spread broadcast
    float o = sbf2[l];
#pragma unroll
    for (int k = 0; k < 32; ++k)
        o = fmaf(sF1[pt * 33 + k], sWf2[k * 16 + l], o);

    out[(size_t)i * 29 + l] = o;
    if (l < DIN) out[(size_t)i * 29 + 16 + l] = x_pfc[i * DIN + l];
}

extern "C" void kernel_launch(void* const* d_in, const int* in_sizes, int n_in,
                              void* d_out, int out_size, void* d_ws, size_t ws_size,
                              hipStream_t stream)
{
    const float* x_pfc = (const float*)d_in[0];
    const float* W1 = (const float*)d_in[1];
    const float* b1 = (const float*)d_in[2];
    const float* W2 = (const float*)d_in[3];
    const float* b2 = (const float*)d_in[4];
    const float* W3 = (const float*)d_in[5];
    const float* b3 = (const float*)d_in[6];
    const float* We = (const float*)d_in[7];
    const float* be = (const float*)d_in[8];
    const float* Wf1 = (const float*)d_in[9];
    const float* bf1 = (const float*)d_in[10];
    const float* Wf2 = (const float*)d_in[11];
    const float* bf2 = (const float*)d_in[12];
    float* out = (float*)d_out;

    float* xw = (float*)d_ws;                         // N*16 f32
    float* ACCa = xw + (size_t)NPTS * 16;             // N*16 f32
    _Float16* Ha = (_Float16*)(ACCa + (size_t)NPTS * 16);  // N*16 f16
    _Float16* La = Ha + (size_t)NPTS * 16;
    _Float16* YHa = La + (size_t)NPTS * 16;
    _Float16* YLa = YHa + (size_t)NPTS * 16;
    float* SQFa = (float*)(YLa + (size_t)NPTS * 16);  // N f32
    unsigned* SQHLa = (unsigned*)(SQFa + NPTS);       // N u32 (packed f16 split)
    unsigned* CVa = SQHLa + NPTS;                     // 2*N*GL u32

    hipLaunchKernelGGL(k_encoder, dim3(NPTS / 64), dim3(64), 0, stream,
                       x_pfc, W1, b1, W2, b2, W3, b3, We, be,
                       xw, Ha, La, YHa, YLa, SQFa, SQHLa, ACCa);
    hipLaunchKernelGGL(k_knn, dim3(NPTS / 32 * 2), dim3(512), 0, stream,
                       Ha, La, YHa, YLa, SQFa, CVa);
    hipLaunchKernelGGL(k_head, dim3(NPTS / 32), dim3(512), 0, stream,
                       xw, CVa, SQFa, x_pfc, ACCa, We, Wf1, bf1, Wf2, bf2, out);
}

// Round 7
// 150.336 us; speedup vs baseline: 1.0171x; 1.0120x over previous
//
#include <hip/hip_runtime.h>
#include <math.h>

#define NPTS 16384
#define DIN 13
#define KNN 8
#define GL 12                 // group-list depth
#define BIGF 1.7014118e38f    // 0x7F000000 — finite sentinel, id bits 0

typedef _Float16 half8 __attribute__((ext_vector_type(8)));
typedef float f32x4 __attribute__((ext_vector_type(4)));
typedef float f32x16 __attribute__((ext_vector_type(16)));

union HU4 { uint4 u; half8 h; };
union C16 { f32x16 w; f32x4 q[4]; };

__device__ __forceinline__ float silu(float v) {
    return v / (1.0f + __expf(-v));
}

#define MED3(v, a, b) __builtin_amdgcn_fmed3f((v), (a), (b))

#define INS8V(v) {                      \
    d7 = MED3((v), d6, d7);             \
    d6 = MED3((v), d5, d6);             \
    d5 = MED3((v), d4, d5);             \
    d4 = MED3((v), d3, d4);             \
    d3 = MED3((v), d2, d3);             \
    d2 = MED3((v), d1, d2);             \
    d1 = MED3((v), d0, d1);             \
    d0 = fminf((v), d0); }

// parameterized 12-deep sorted-insert (G##0..G##11)
#define INS12L(G, v) {                  \
    G##11 = MED3((v), G##10, G##11);    \
    G##10 = MED3((v), G##9, G##10);     \
    G##9  = MED3((v), G##8, G##9);      \
    G##8  = MED3((v), G##7, G##8);      \
    G##7  = MED3((v), G##6, G##7);      \
    G##6  = MED3((v), G##5, G##6);      \
    G##5  = MED3((v), G##4, G##5);      \
    G##4  = MED3((v), G##3, G##4);      \
    G##3  = MED3((v), G##2, G##3);      \
    G##2  = MED3((v), G##1, G##2);      \
    G##1  = MED3((v), G##0, G##1);      \
    G##0  = fminf((v), G##0); }

#define INS12G(v) INS12L(g, v)

#define CSW(p, q) { float lo_ = fminf(m##p, m##q); float hi_ = fmaxf(m##p, m##q); m##p = lo_; m##q = hi_; }

#define CLEAN16() \
    CSW(0,8) CSW(1,9) CSW(2,10) CSW(3,11) CSW(4,12) CSW(5,13) CSW(6,14) CSW(7,15) \
    CSW(0,4) CSW(1,5) CSW(2,6) CSW(3,7) CSW(8,12) CSW(9,13) CSW(10,14) CSW(11,15) \
    CSW(0,2) CSW(1,3) CSW(4,6) CSW(5,7) CSW(8,10) CSW(9,11) CSW(12,14) CSW(13,15) \
    CSW(0,1) CSW(2,3) CSW(4,5) CSW(6,7) CSW(8,9) CSW(10,11) CSW(12,13) CSW(14,15)

#define MERGE12_SHFLG(G, mask) {                              \
    float b0 = __shfl_xor(G##0, (mask), 64);                  \
    float b1 = __shfl_xor(G##1, (mask), 64);                  \
    float b2 = __shfl_xor(G##2, (mask), 64);                  \
    float b3 = __shfl_xor(G##3, (mask), 64);                  \
    float b4 = __shfl_xor(G##4, (mask), 64);                  \
    float b5 = __shfl_xor(G##5, (mask), 64);                  \
    float b6 = __shfl_xor(G##6, (mask), 64);                  \
    float b7 = __shfl_xor(G##7, (mask), 64);                  \
    float b8 = __shfl_xor(G##8, (mask), 64);                  \
    float b9 = __shfl_xor(G##9, (mask), 64);                  \
    float b10 = __shfl_xor(G##10, (mask), 64);                \
    float b11 = __shfl_xor(G##11, (mask), 64);                \
    float m0 = G##0, m1 = G##1, m2 = G##2, m3 = G##3;         \
    float m4 = fminf(G##4, b11), m5 = fminf(G##5, b10);       \
    float m6 = fminf(G##6, b9),  m7 = fminf(G##7, b8);        \
    float m8 = fminf(G##8, b7),  m9 = fminf(G##9, b6);        \
    float m10 = fminf(G##10, b5), m11 = fminf(G##11, b4);     \
    float m12 = b3, m13 = b2, m14 = b1, m15 = b0;             \
    CLEAN16();                                                \
    G##0 = m0; G##1 = m1; G##2 = m2; G##3 = m3;               \
    G##4 = m4; G##5 = m5; G##6 = m6; G##7 = m7;               \
    G##8 = m8; G##9 = m9; G##10 = m10; G##11 = m11; }

#define MERGE12_SHFL(mask) MERGE12_SHFLG(g, mask)

#define MERGE12_LDSG(G, LD) {                                 \
    float b0 = LD(0), b1 = LD(1), b2 = LD(2), b3 = LD(3);     \
    float b4 = LD(4), b5 = LD(5), b6 = LD(6), b7 = LD(7);     \
    float b8 = LD(8), b9 = LD(9), b10 = LD(10), b11 = LD(11); \
    float m0 = G##0, m1 = G##1, m2 = G##2, m3 = G##3;         \
    float m4 = fminf(G##4, b11), m5 = fminf(G##5, b10);       \
    float m6 = fminf(G##6, b9),  m7 = fminf(G##7, b8);        \
    float m8 = fminf(G##8, b7),  m9 = fminf(G##9, b6);        \
    float m10 = fminf(G##10, b5), m11 = fminf(G##11, b4);     \
    float m12 = b3, m13 = b2, m14 = b1, m15 = b0;             \
    CLEAN16();                                                \
    G##0 = m0; G##1 = m1; G##2 = m2; G##3 = m3;               \
    G##4 = m4; G##5 = m5; G##6 = m6; G##7 = m7;               \
    G##8 = m8; G##9 = m9; G##10 = m10; G##11 = m11; }

#define MERGE12_LDS(LD) MERGE12_LDSG(g, LD)

#define MERGE8(mask) {                                   \
    float b0 = __shfl_xor(d0, (mask), 64);               \
    float b1 = __shfl_xor(d1, (mask), 64);               \
    float b2 = __shfl_xor(d2, (mask), 64);               \
    float b3 = __shfl_xor(d3, (mask), 64);               \
    float b4 = __shfl_xor(d4, (mask), 64);               \
    float b5 = __shfl_xor(d5, (mask), 64);               \
    float b6 = __shfl_xor(d6, (mask), 64);               \
    float b7 = __shfl_xor(d7, (mask), 64);               \
    float m0 = fminf(d0, b7), m1 = fminf(d1, b6);        \
    float m2 = fminf(d2, b5), m3 = fminf(d3, b4);        \
    float m4 = fminf(d4, b3), m5 = fminf(d5, b2);        \
    float m6 = fminf(d6, b1), m7 = fminf(d7, b0);        \
    CSW(0,4) CSW(1,5) CSW(2,6) CSW(3,7)                  \
    CSW(0,2) CSW(1,3) CSW(4,6) CSW(5,7)                  \
    CSW(0,1) CSW(2,3) CSW(4,5) CSW(6,7)                  \
    d0 = m0; d1 = m1; d2 = m2; d3 = m3;                  \
    d4 = m4; d5 = m5; d6 = m6; d7 = m7; }

// ---- K1: encoder MLP -> x, H/L/YH/YL f16 splits, SQF, packed SQHL, ACC ----
__global__ __launch_bounds__(64) void k_encoder(
    const float* __restrict__ x_pfc,
    const float* __restrict__ W1, const float* __restrict__ b1,
    const float* __restrict__ W2, const float* __restrict__ b2,
    const float* __restrict__ W3, const float* __restrict__ b3,
    const float* __restrict__ We, const float* __restrict__ be,
    float* __restrict__ xo, _Float16* __restrict__ H, _Float16* __restrict__ L,
    _Float16* __restrict__ YH, _Float16* __restrict__ YL,
    float* __restrict__ SQF, unsigned* __restrict__ SQHL,
    float* __restrict__ ACC)
{
    __shared__ float sW1[DIN * 8];
    __shared__ float sb1[8];
    __shared__ float sW2[8 * 16];
    __shared__ float sb2[16];
    __shared__ float sW3[16 * 15];
    __shared__ float sb3[15];
    __shared__ float sWe[16 * 16];
    __shared__ float sbe[16];
    int t = threadIdx.x;
    for (int q = t; q < DIN * 8; q += 64) sW1[q] = W1[q];
    for (int q = t; q < 8; q += 64) sb1[q] = b1[q];
    for (int q = t; q < 8 * 16; q += 64) sW2[q] = W2[q];
    for (int q = t; q < 16; q += 64) sb2[q] = b2[q];
    for (int q = t; q < 16 * 15; q += 64) sW3[q] = W3[q];
    for (int q = t; q < 15; q += 64) sb3[q] = b3[q];
    for (int q = t; q < 16 * 16; q += 64) sWe[q] = We[q];
    for (int q = t; q < 16; q += 64) sbe[q] = be[q];
    __syncthreads();

    int i = blockIdx.x * 64 + t;
    float in[DIN];
#pragma unroll
    for (int d = 0; d < DIN; ++d) in[d] = x_pfc[i * DIN + d];

    float a1[8];
#pragma unroll
    for (int h = 0; h < 8; ++h) a1[h] = sb1[h];
#pragma unroll
    for (int d = 0; d < DIN; ++d) {
        float v = in[d];
#pragma unroll
        for (int h = 0; h < 8; ++h) a1[h] += v * sW1[d * 8 + h];
    }
#pragma unroll
    for (int h = 0; h < 8; ++h) a1[h] = silu(a1[h]);

    float a2[16];
#pragma unroll
    for (int h = 0; h < 16; ++h) a2[h] = sb2[h];
#pragma unroll
    for (int d = 0; d < 8; ++d) {
        float v = a1[d];
#pragma unroll
        for (int h = 0; h < 16; ++h) a2[h] += v * sW2[d * 16 + h];
    }
#pragma unroll
    for (int h = 0; h < 16; ++h) a2[h] = silu(a2[h]);

    float a3[15];
#pragma unroll
    for (int h = 0; h < 15; ++h) a3[h] = sb3[h];
#pragma unroll
    for (int d = 0; d < 16; ++d) {
        float v = a2[d];
#pragma unroll
        for (int h = 0; h < 15; ++h) a3[h] += v * sW3[d * 15 + h];
    }

    float xr[16];
#pragma unroll
    for (int h = 0; h < 15; ++h) xr[h] = a3[h];
    xr[15] = in[DIN - 1];

    float s = 0.0f;
#pragma unroll
    for (int d = 0; d < 16; ++d) s += xr[d] * xr[d];

    float accb[16];
#pragma unroll
    for (int h = 0; h < 16; ++h) accb[h] = sbe[h];
#pragma unroll
    for (int d = 0; d < 16; ++d) {
        float v = xr[d];
#pragma unroll
        for (int h = 0; h < 16; ++h) accb[h] += v * sWe[d * 16 + h];
    }

    _Float16 hb[16], lb[16], yhb[16], ylb[16];
#pragma unroll
    for (int d = 0; d < 16; ++d) {
        _Float16 h = (_Float16)xr[d];
        hb[d] = h;
        lb[d] = (_Float16)(xr[d] - (float)h);
        float y = -2.0f * xr[d];
        _Float16 yh = (_Float16)y;
        yhb[d] = yh;
        ylb[d] = (_Float16)(y - (float)yh);
    }
    {
        uint4* p;
        p = (uint4*)(H + (size_t)i * 16);  p[0] = ((uint4*)hb)[0];  p[1] = ((uint4*)hb)[1];
        p = (uint4*)(L + (size_t)i * 16);  p[0] = ((uint4*)lb)[0];  p[1] = ((uint4*)lb)[1];
        p = (uint4*)(YH + (size_t)i * 16); p[0] = ((uint4*)yhb)[0]; p[1] = ((uint4*)yhb)[1];
        p = (uint4*)(YL + (size_t)i * 16); p[0] = ((uint4*)ylb)[0]; p[1] = ((uint4*)ylb)[1];
        f32x4* xq = (f32x4*)(xo + (size_t)i * 16);
        f32x4* aq = (f32x4*)(ACC + (size_t)i * 16);
#pragma unroll
        for (int q = 0; q < 4; ++q) {
            f32x4 xv, av;
#pragma unroll
            for (int r = 0; r < 4; ++r) { xv[r] = xr[q * 4 + r]; av[r] = accb[q * 4 + r]; }
            xq[q] = xv;
            aq[q] = av;
        }
    }
    SQF[i] = s;
    {
        // packed f16 hi/lo split of sq: low16 = sqh, high16 = sql
        _Float16 sh = (_Float16)s;
        _Float16 sl = (_Float16)(s - (float)sh);
        unsigned uh = *(const unsigned short*)&sh;
        unsigned ul = *(const unsigned short*)&sl;
        SQHL[i] = (ul << 16) | uh;
    }
}

// ---- K2: MFMA 32x32 KNN ----
// Round-19: j-tile reuse across TWO i-tiles. Rounds 16-18 micro-opts were
// neutral; pipe arithmetic showed L2 read demand (~512MB aggregate, ~15us)
// ~= MFMA demand ~= VALU demand, with poor overlap (serial per-tile chain).
// Now: 64 i-points/block (grid 512 = 256 ih x 2 jh). Each loaded Ah/Al
// feeds two independent 3-MFMA chains (i-tiles A and B):
//  - L2 traffic halves (512->256 MB)
//  - per-tile load/address overhead amortizes over 2 outputs
//  - 2 independent MFMA + med3 chains double ILP (attacks serialization)
// Group-id encoding unchanged (ids are j-coords only) -> k_head untouched.
// Merge tree: 24 slots/wave (6144 f32) aliased in the 32KB sq buffer.
__global__ __launch_bounds__(512, 4) void k_knn(
    const _Float16* __restrict__ H, const _Float16* __restrict__ L,
    const _Float16* __restrict__ YH, const _Float16* __restrict__ YL,
    const float* __restrict__ SQF, unsigned* __restrict__ CV)
{
    __shared__ float sBuf[8192];   // loop: f32 sq of j-half; after: merge tree

    int t = threadIdx.x;
    int w = t >> 6;
    int lane = t & 63;
    int r31 = lane & 31;
    int hh = lane >> 5;
    int ih = blockIdx.x >> 1;      // 0..255
    int jh = blockIdx.x & 1;
    int i0 = ih * 64;

    int giA = i0 + r31;
    int giB = i0 + 32 + r31;
    half8 B1A = *(const half8*)(YH + (size_t)giA * 16 + hh * 8);
    half8 B2A = *(const half8*)(YL + (size_t)giA * 16 + hh * 8);
    half8 B1B = *(const half8*)(YH + (size_t)giB * 16 + hh * 8);
    half8 B2B = *(const half8*)(YL + (size_t)giB * 16 + hh * 8);

    // stage sq (f32) for this block's j-half: 2048 x f32x4, coalesced
    {
        const f32x4* src = (const f32x4*)(SQF + jh * 8192);
        f32x4* dst = (f32x4*)sBuf;
        for (int q = t; q < 2048; q += 512) dst[q] = src[q];
    }

    float gA0 = BIGF, gA1 = BIGF, gA2 = BIGF, gA3 = BIGF;
    float gA4 = BIGF, gA5 = BIGF, gA6 = BIGF, gA7 = BIGF;
    float gA8 = BIGF, gA9 = BIGF, gA10 = BIGF, gA11 = BIGF;
    float gB0 = BIGF, gB1 = BIGF, gB2 = BIGF, gB3 = BIGF;
    float gB4 = BIGF, gB5 = BIGF, gB6 = BIGF, gB7 = BIGF;
    float gB8 = BIGF, gB9 = BIGF, gB10 = BIGF, gB11 = BIGF;

    int jw = jh * 8192 + w * 1024;
    const _Float16* pH = H + ((size_t)(jw + r31)) * 16 + hh * 8;
    const _Float16* pL = L + ((size_t)(jw + r31)) * 16 + hh * 8;
    const float* sqb = sBuf + w * 1024 + hh * 4;
    unsigned idt = (unsigned)((w << 1) | hh);

    __syncthreads();   // sq staged

#pragma unroll 2
    for (int tt = 0; tt < 32; ++tt) {
        half8 Ah = *(const half8*)(pH + (size_t)tt * 512);
        half8 Al = *(const half8*)(pL + (size_t)tt * 512);
        const f32x4* s_ = (const f32x4*)(sqb + tt * 32);
        f32x4 s0 = s_[0], s1 = s_[2], s2 = s_[4], s3 = s_[6];

        C16 cA, cB;
        cA.q[0] = s0; cA.q[1] = s1; cA.q[2] = s2; cA.q[3] = s3;
        cB.q[0] = s0; cB.q[1] = s1; cB.q[2] = s2; cB.q[3] = s3;
        cA.w = __builtin_amdgcn_mfma_f32_32x32x16_f16(Ah, B1A, cA.w, 0, 0, 0);
        cB.w = __builtin_amdgcn_mfma_f32_32x32x16_f16(Ah, B1B, cB.w, 0, 0, 0);
        cA.w = __builtin_amdgcn_mfma_f32_32x32x16_f16(Al, B1A, cA.w, 0, 0, 0);
        cB.w = __builtin_amdgcn_mfma_f32_32x32x16_f16(Al, B1B, cB.w, 0, 0, 0);
        cA.w = __builtin_amdgcn_mfma_f32_32x32x16_f16(Ah, B2A, cA.w, 0, 0, 0);
        cB.w = __builtin_amdgcn_mfma_f32_32x32x16_f16(Ah, B2B, cB.w, 0, 0, 0);

        unsigned idc = idt + (unsigned)(tt << 4);
        {
            float v0 = fminf(fminf(cA.w[0], cA.w[1]), cA.w[2]);
            float v1 = fminf(fminf(cA.w[3], cA.w[4]), cA.w[5]);
            float v2 = fminf(fminf(cA.w[6], cA.w[7]), cA.w[8]);
            float v3 = fminf(fminf(cA.w[9], cA.w[10]), cA.w[11]);
            float v4 = fminf(fminf(cA.w[12], cA.w[13]), cA.w[14]);
            float v5 = fminf(fminf(v0, v1), cA.w[15]);
            float v6 = fminf(fminf(v2, v3), v4);
            float vmin = fminf(v5, v6);
            unsigned pk = (__float_as_uint(vmin) & 0xFFFFFC00u) | idc;
            float pf = __uint_as_float(pk);
            INS12L(gA, pf);
        }
        {
            float v0 = fminf(fminf(cB.w[0], cB.w[1]), cB.w[2]);
            float v1 = fminf(fminf(cB.w[3], cB.w[4]), cB.w[5]);
            float v2 = fminf(fminf(cB.w[6], cB.w[7]), cB.w[8]);
            float v3 = fminf(fminf(cB.w[9], cB.w[10]), cB.w[11]);
            float v4 = fminf(fminf(cB.w[12], cB.w[13]), cB.w[14]);
            float v5 = fminf(fminf(v0, v1), cB.w[15]);
            float v6 = fminf(fminf(v2, v3), v4);
            float vmin = fminf(v5, v6);
            unsigned pk = (__float_as_uint(vmin) & 0xFFFFFC00u) | idc;
            float pf = __uint_as_float(pk);
            INS12L(gB, pf);
        }
    }

    MERGE12_SHFLG(gA, 32);
    MERGE12_SHFLG(gB, 32);

    __syncthreads();   // sq reads done everywhere; sBuf reusable as merge tree

#define STORE24() if (lane < 32) {                         \
        sBuf[(w * 24 + 0) * 32 + r31] = gA0;               \
        sBuf[(w * 24 + 1) * 32 + r31] = gA1;               \
        sBuf[(w * 24 + 2) * 32 + r31] = gA2;               \
        sBuf[(w * 24 + 3) * 32 + r31] = gA3;               \
        sBuf[(w * 24 + 4) * 32 + r31] = gA4;               \
        sBuf[(w * 24 + 5) * 32 + r31] = gA5;               \
        sBuf[(w * 24 + 6) * 32 + r31] = gA6;               \
        sBuf[(w * 24 + 7) * 32 + r31] = gA7;               \
        sBuf[(w * 24 + 8) * 32 + r31] = gA8;               \
        sBuf[(w * 24 + 9) * 32 + r31] = gA9;               \
        sBuf[(w * 24 + 10) * 32 + r31] = gA10;             \
        sBuf[(w * 24 + 11) * 32 + r31] = gA11;             \
        sBuf[(w * 24 + 12) * 32 + r31] = gB0;              \
        sBuf[(w * 24 + 13) * 32 + r31] = gB1;              \
        sBuf[(w * 24 + 14) * 32 + r31] = gB2;              \
        sBuf[(w * 24 + 15) * 32 + r31] = gB3;              \
        sBuf[(w * 24 + 16) * 32 + r31] = gB4;              \
        sBuf[(w * 24 + 17) * 32 + r31] = gB5;              \
        sBuf[(w * 24 + 18) * 32 + r31] = gB6;              \
        sBuf[(w * 24 + 19) * 32 + r31] = gB7;              \
        sBuf[(w * 24 + 20) * 32 + r31] = gB8;              \
        sBuf[(w * 24 + 21) * 32 + r31] = gB9;              \
        sBuf[(w * 24 + 22) * 32 + r31] = gB10;             \
        sBuf[(w * 24 + 23) * 32 + r31] = gB11; }

#define MERGE_STEP(pw) {                                   \
        int pw_ = (pw);                                    \
        const float* mb = sBuf + (pw_ * 24) * 32 + r31;    \
        { _Pragma("clang diagnostic push")                 \
          ; }                                              \
        {                                                  \
        }                                                  \
    }

    if (w >= 4) STORE24();
    __syncthreads();
    if (w < 4) {
        int pw = w + 4;
#define LDA(s) sBuf[(pw * 24 + (s)) * 32 + r31]
#define LDB(s) sBuf[(pw * 24 + 12 + (s)) * 32 + r31]
        MERGE12_LDSG(gA, LDA);
        MERGE12_LDSG(gB, LDB);
#undef LDA
#undef LDB
    }
    __syncthreads();
    if (w == 2 || w == 3) STORE24();
    __syncthreads();
    if (w < 2) {
        int pw = w + 2;
#define LDA(s) sBuf[(pw * 24 + (s)) * 32 + r31]
#define LDB(s) sBuf[(pw * 24 + 12 + (s)) * 32 + r31]
        MERGE12_LDSG(gA, LDA);
        MERGE12_LDSG(gB, LDB);
#undef LDA
#undef LDB
    }
    __syncthreads();
    if (w == 1) STORE24();
    __syncthreads();
    if (w == 0) {
        int pw = 1;
#define LDA(s) sBuf[(pw * 24 + (s)) * 32 + r31]
#define LDB(s) sBuf[(pw * 24 + 12 + (s)) * 32 + r31]
        MERGE12_LDSG(gA, LDA);
        MERGE12_LDSG(gB, LDB);
#undef LDA
#undef LDB
        if (lane < 32) {
            unsigned jb = ((unsigned)jh) << 9;
            size_t baseA = ((size_t)jh * NPTS + (i0 + r31)) * GL;
            size_t baseB = ((size_t)jh * NPTS + (i0 + 32 + r31)) * GL;
            CV[baseA + 0] = __float_as_uint(gA0) | jb;
            CV[baseA + 1] = __float_as_uint(gA1) | jb;
            CV[baseA + 2] = __float_as_uint(gA2) | jb;
            CV[baseA + 3] = __float_as_uint(gA3) | jb;
            CV[baseA + 4] = __float_as_uint(gA4) | jb;
            CV[baseA + 5] = __float_as_uint(gA5) | jb;
            CV[baseA + 6] = __float_as_uint(gA6) | jb;
            CV[baseA + 7] = __float_as_uint(gA7) | jb;
            CV[baseA + 8] = __float_as_uint(gA8) | jb;
            CV[baseA + 9] = __float_as_uint(gA9) | jb;
            CV[baseA + 10] = __float_as_uint(gA10) | jb;
            CV[baseA + 11] = __float_as_uint(gA11) | jb;
            CV[baseB + 0] = __float_as_uint(gB0) | jb;
            CV[baseB + 1] = __float_as_uint(gB1) | jb;
            CV[baseB + 2] = __float_as_uint(gB2) | jb;
            CV[baseB + 3] = __float_as_uint(gB3) | jb;
            CV[baseB + 4] = __float_as_uint(gB4) | jb;
            CV[baseB + 5] = __float_as_uint(gB5) | jb;
            CV[baseB + 6] = __float_as_uint(gB6) | jb;
            CV[baseB + 7] = __float_as_uint(gB7) | jb;
            CV[baseB + 8] = __float_as_uint(gB8) | jb;
            CV[baseB + 9] = __float_as_uint(gB9) | jb;
            CV[baseB + 10] = __float_as_uint(gB10) | jb;
            CV[baseB + 11] = __float_as_uint(gB11) | jb;
        }
    }
#undef STORE24
#undef MERGE_STEP
}

// ---- K3: group re-eval + exact top-8 + edge conv + head MLP ----
// (unchanged from round 15 — scratch-free epilogue, 16 lanes/point)
__global__ __launch_bounds__(512, 4) void k_head(
    const float* __restrict__ x, const unsigned* __restrict__ CV,
    const float* __restrict__ SQF,
    const float* __restrict__ x_pfc, const float* __restrict__ ACC,
    const float* __restrict__ We,
    const float* __restrict__ Wf1, const float* __restrict__ bf1,
    const float* __restrict__ Wf2, const float* __restrict__ bf2,
    float* __restrict__ out)
{
    __shared__ float sWe2[16 * 16];
    __shared__ float sWf1[16 * 32];
    __shared__ float sbf1[32];
    __shared__ float sWf2[32 * 16];
    __shared__ float sbf2[16];
    __shared__ int sGrp[32][GL];       // pre-decoded jb bases
    __shared__ int cnt[32];
    __shared__ int sIdx[32 * 8];
    __shared__ float sF1[32 * 33];     // f1 stage, stride 33 (conflict-free)
    int t = threadIdx.x;
    for (int q = t; q < 16 * 16; q += 512) sWe2[q] = We[256 + q];
    for (int q = t; q < 16 * 32; q += 512) sWf1[q] = Wf1[q];
    for (int q = t; q < 32; q += 512) sbf1[q] = bf1[q];
    for (int q = t; q < 32 * 16; q += 512) sWf2[q] = Wf2[q];
    for (int q = t; q < 16; q += 512) sbf2[q] = bf2[q];

    int i0 = blockIdx.x * 32;

    // preamble: 2 threads/point merge the two sorted CV half-lists (wave 0)
    if (t < 64) {
        int pi = t & 31;
        int hf = t >> 5;
        const f32x4* c = (const f32x4*)(CV + ((size_t)hf * NPTS + (i0 + pi)) * GL);
        f32x4 c0 = c[0], c1 = c[1], c2 = c[2];
        float g0 = c0[0], g1 = c0[1], g2 = c0[2], g3 = c0[3];
        float g4 = c1[0], g5 = c1[1], g6 = c1[2], g7 = c1[3];
        float g8 = c2[0], g9 = c2[1], g10 = c2[2], g11 = c2[3];
        MERGE12_SHFL(32);
        if (t < 32) {
            cnt[pi] = 0;
#define DECJB(gk, s) { unsigned id_ = __float_as_uint(gk) & 0x3FFu;          \
            sGrp[pi][s] = (int)(((id_ >> 9) & 1) * 8192 + ((id_ >> 1) & 7) * 1024 + \
                                ((id_ >> 4) & 31) * 32 + (id_ & 1) * 4); }
            DECJB(g0, 0) DECJB(g1, 1) DECJB(g2, 2) DECJB(g3, 3)
            DECJB(g4, 4) DECJB(g5, 5) DECJB(g6, 6) DECJB(g7, 7)
            DECJB(g8, 8) DECJB(g9, 9) DECJB(g10, 10) DECJB(g11, 11)
#undef DECJB
        }
    }
    __syncthreads();

    int l = t & 15;          // lane within point
    int pt = t >> 4;         // point within block (0..31)
    int ql = l & 3;          // quarter within row
    int qd = l >> 2;         // row within run
    int i = i0 + pt;

    float xi[16];
    {
        const f32x4* xiv = (const f32x4*)(x + (size_t)i * 16);
#pragma unroll
        for (int q = 0; q < 4; ++q) {
            f32x4 a = xiv[q];
#pragma unroll
            for (int r = 0; r < 4; ++r) xi[q * 4 + r] = a[r];
        }
    }
    // this lane's quarter of xi (runtime ql -> memory load, not reg idx)
    f32x4 xiq = ((const f32x4*)(x + (size_t)i * 16))[ql];

    // scan A: 12 groups x 4 coalesced runs; per-lane top-8 over owned vals
    float val[12];
    float d0 = BIGF, d1 = BIGF, d2 = BIGF, d3 = BIGF;
    float d4 = BIGF, d5 = BIGF, d6 = BIGF, d7 = BIGF;
#pragma unroll
    for (int g = 0; g < GL; ++g) {
        int jb = sGrp[pt][g];
        float vg = BIGF;
#pragma unroll
        for (int rho = 0; rho < 4; ++rho) {
            // run of 4 rows (256B) at jb+rho*8: lane l takes 16B at +l*16
            f32x4 a = *((const f32x4*)(x + ((size_t)(jb + rho * 8)) * 16) + l);
            float qdot = xiq[0] * a[0];
            qdot = fmaf(xiq[1], a[1], qdot);
            qdot = fmaf(xiq[2], a[2], qdot);
            qdot = fmaf(xiq[3], a[3], qdot);
            qdot += __shfl_xor(qdot, 1, 64);
            qdot += __shfl_xor(qdot, 2, 64);
            float v = fmaf(qdot, -2.0f, SQF[jb + rho * 8 + qd]);
            vg = (ql == rho) ? v : vg;   // owner keeps candidate (rho==ql, qd)
        }
        val[g] = vg;
        INS8V(vg);
    }

    // exact kth over the point's 192 candidates (16-lane butterfly)
    MERGE8(1);
    MERGE8(2);
    MERGE8(4);
    MERGE8(8);
    float kth = d7;

    // scan B: register re-scan, collect ids
#pragma unroll
    for (int g = 0; g < GL; ++g) {
        float v = val[g];
        if (v <= kth) {
            int j = sGrp[pt][g] + ql * 8 + qd;
            int p = atomicAdd(&cnt[pt], 1);
            if (p < KNN) sIdx[pt * 8 + p] = j;
        }
    }
    __syncthreads();

    int e8 = l & 7;
    int j = sIdx[pt * 8 + e8];

    float xd[16];
    {
        const f32x4* xjv = (const f32x4*)(x + (size_t)j * 16);
#pragma unroll
        for (int q = 0; q < 4; ++q) {
            f32x4 a = xjv[q];
#pragma unroll
            for (int r = 0; r < 4; ++r) xd[q * 4 + r] = a[r] - xi[q * 4 + r];
        }
    }

    float acc[16];
    {
        const f32x4* av = (const f32x4*)(ACC + (size_t)i * 16);
#pragma unroll
        for (int q = 0; q < 4; ++q) {
            f32x4 a = av[q];
#pragma unroll
            for (int r = 0; r < 4; ++r) acc[q * 4 + r] = a[r];
        }
    }
#pragma unroll
    for (int d = 0; d < 16; ++d) {
        float v = xd[d];
#pragma unroll
        for (int h = 0; h < 16; ++h) acc[h] += v * sWe2[d * 16 + h];
    }

    float feats[16];
#pragma unroll
    for (int h = 0; h < 16; ++h) feats[h] = silu(acc[h]);

    // mean over 8 edges (lanes 8..15 hold duplicate msgs -> same mean;
    // feats identical across all 16 lanes of the point afterwards)
#pragma unroll
    for (int mask = 1; mask <= 4; mask <<= 1) {
#pragma unroll
        for (int h = 0; h < 16; ++h) feats[h] += __shfl_xor(feats[h], mask, 64);
    }
#pragma unroll
    for (int h = 0; h < 16; ++h) feats[h] *= 0.125f;

    // f1: lane l computes outputs l and l+16 (Wf1 reads broadcast per k)
    float p0 = sbf1[l];
    float p1 = sbf1[l + 16];
#pragma unroll
    for (int k = 0; k < 16; ++k) {
        float v = feats[k];
        p0 = fmaf(v, sWf1[k * 32 + l], p0);
        p1 = fmaf(v, sWf1[k * 32 + l + 16], p1);
    }
    p0 = silu(p0);
    p1 = silu(p1);
    sF1[pt * 33 + l] = p0;
    sF1[pt * 33 + 16 + l] = p1;
    __syncthreads();

    // f2: lane l computes output l; sF1 reads are 4-bank-spread broadcast
    float o = sbf2[l];
#pragma unroll
    for (int k = 0; k < 32; ++k)
        o = fmaf(sF1[pt * 33 + k], sWf2[k * 16 + l], o);

    out[(size_t)i * 29 + l] = o;
    if (l < DIN) out[(size_t)i * 29 + 16 + l] = x_pfc[i * DIN + l];
}

extern "C" void kernel_launch(void* const* d_in, const int* in_sizes, int n_in,
                              void* d_out, int out_size, void* d_ws, size_t ws_size,
                              hipStream_t stream)
{
    const float* x_pfc = (const float*)d_in[0];
    const float* W1 = (const float*)d_in[1];
    const float* b1 = (const float*)d_in[2];
    const float* W2 = (const float*)d_in[3];
    const float* b2 = (const float*)d_in[4];
    const float* W3 = (const float*)d_in[5];
    const float* b3 = (const float*)d_in[6];
    const float* We = (const float*)d_in[7];
    const float* be = (const float*)d_in[8];
    const float* Wf1 = (const float*)d_in[9];
    const float* bf1 = (const float*)d_in[10];
    const float* Wf2 = (const float*)d_in[11];
    const float* bf2 = (const float*)d_in[12];
    float* out = (float*)d_out;

    float* xw = (float*)d_ws;                         // N*16 f32
    float* ACCa = xw + (size_t)NPTS * 16;             // N*16 f32
    _Float16* Ha = (_Float16*)(ACCa + (size_t)NPTS * 16);  // N*16 f16
    _Float16* La = Ha + (size_t)NPTS * 16;
    _Float16* YHa = La + (size_t)NPTS * 16;
    _Float16* YLa = YHa + (size_t)NPTS * 16;
    float* SQFa = (float*)(YLa + (size_t)NPTS * 16);  // N f32
    unsigned* SQHLa = (unsigned*)(SQFa + NPTS);       // N u32 (packed f16 split)
    unsigned* CVa = SQHLa + NPTS;                     // 2*N*GL u32

    hipLaunchKernelGGL(k_encoder, dim3(NPTS / 64), dim3(64), 0, stream,
                       x_pfc, W1, b1, W2, b2, W3, b3, We, be,
                       xw, Ha, La, YHa, YLa, SQFa, SQHLa, ACCa);
    hipLaunchKernelGGL(k_knn, dim3(NPTS / 64 * 2), dim3(512), 0, stream,
                       Ha, La, YHa, YLa, SQFa, CVa);
    hipLaunchKernelGGL(k_head, dim3(NPTS / 32), dim3(512), 0, stream,
                       xw, CVa, SQFa, x_pfc, ACCa, We, Wf1, bf1, Wf2, bf2, out);
}

// Round 9
// 139.620 us; speedup vs baseline: 1.0952x; 1.0768x over previous
//
#include <hip/hip_runtime.h>
#include <math.h>

#define NPTS 16384
#define DIN 13
#define KNN 8
#define GL 12                 // group-list depth
#define BIGF 1.7014118e38f    // 0x7F000000 — finite sentinel, id bits 0

typedef _Float16 half8 __attribute__((ext_vector_type(8)));
typedef float f32x4 __attribute__((ext_vector_type(4)));
typedef float f32x16 __attribute__((ext_vector_type(16)));

union C16 { f32x16 w; f32x4 q[4]; };

__device__ __forceinline__ float silu(float v) {
    return v / (1.0f + __expf(-v));
}

#define MED3(v, a, b) __builtin_amdgcn_fmed3f((v), (a), (b))

#define INS8V(v) {                      \
    d7 = MED3((v), d6, d7);             \
    d6 = MED3((v), d5, d6);             \
    d5 = MED3((v), d4, d5);             \
    d4 = MED3((v), d3, d4);             \
    d3 = MED3((v), d2, d3);             \
    d2 = MED3((v), d1, d2);             \
    d1 = MED3((v), d0, d1);             \
    d0 = fminf((v), d0); }

// parameterized 12-deep sorted-insert (G##0..G##11)
#define INS12L(G, v) {                  \
    G##11 = MED3((v), G##10, G##11);    \
    G##10 = MED3((v), G##9, G##10);     \
    G##9  = MED3((v), G##8, G##9);      \
    G##8  = MED3((v), G##7, G##8);      \
    G##7  = MED3((v), G##6, G##7);      \
    G##6  = MED3((v), G##5, G##6);      \
    G##5  = MED3((v), G##4, G##5);      \
    G##4  = MED3((v), G##3, G##4);      \
    G##3  = MED3((v), G##2, G##3);      \
    G##2  = MED3((v), G##1, G##2);      \
    G##1  = MED3((v), G##0, G##1);      \
    G##0  = fminf((v), G##0); }

#define CSW(p, q) { float lo_ = fminf(m##p, m##q); float hi_ = fmaxf(m##p, m##q); m##p = lo_; m##q = hi_; }

#define CLEAN16() \
    CSW(0,8) CSW(1,9) CSW(2,10) CSW(3,11) CSW(4,12) CSW(5,13) CSW(6,14) CSW(7,15) \
    CSW(0,4) CSW(1,5) CSW(2,6) CSW(3,7) CSW(8,12) CSW(9,13) CSW(10,14) CSW(11,15) \
    CSW(0,2) CSW(1,3) CSW(4,6) CSW(5,7) CSW(8,10) CSW(9,11) CSW(12,14) CSW(13,15) \
    CSW(0,1) CSW(2,3) CSW(4,5) CSW(6,7) CSW(8,9) CSW(10,11) CSW(12,13) CSW(14,15)

#define MERGE12_SHFLG(G, mask) {                              \
    float b0 = __shfl_xor(G##0, (mask), 64);                  \
    float b1 = __shfl_xor(G##1, (mask), 64);                  \
    float b2 = __shfl_xor(G##2, (mask), 64);                  \
    float b3 = __shfl_xor(G##3, (mask), 64);                  \
    float b4 = __shfl_xor(G##4, (mask), 64);                  \
    float b5 = __shfl_xor(G##5, (mask), 64);                  \
    float b6 = __shfl_xor(G##6, (mask), 64);                  \
    float b7 = __shfl_xor(G##7, (mask), 64);                  \
    float b8 = __shfl_xor(G##8, (mask), 64);                  \
    float b9 = __shfl_xor(G##9, (mask), 64);                  \
    float b10 = __shfl_xor(G##10, (mask), 64);                \
    float b11 = __shfl_xor(G##11, (mask), 64);                \
    float m0 = G##0, m1 = G##1, m2 = G##2, m3 = G##3;         \
    float m4 = fminf(G##4, b11), m5 = fminf(G##5, b10);       \
    float m6 = fminf(G##6, b9),  m7 = fminf(G##7, b8);        \
    float m8 = fminf(G##8, b7),  m9 = fminf(G##9, b6);        \
    float m10 = fminf(G##10, b5), m11 = fminf(G##11, b4);     \
    float m12 = b3, m13 = b2, m14 = b1, m15 = b0;             \
    CLEAN16();                                                \
    G##0 = m0; G##1 = m1; G##2 = m2; G##3 = m3;               \
    G##4 = m4; G##5 = m5; G##6 = m6; G##7 = m7;               \
    G##8 = m8; G##9 = m9; G##10 = m10; G##11 = m11; }

#define MERGE12_LDSG(G, LD) {                                 \
    float b0 = LD(0), b1 = LD(1), b2 = LD(2), b3 = LD(3);     \
    float b4 = LD(4), b5 = LD(5), b6 = LD(6), b7 = LD(7);     \
    float b8 = LD(8), b9 = LD(9), b10 = LD(10), b11 = LD(11); \
    float m0 = G##0, m1 = G##1, m2 = G##2, m3 = G##3;         \
    float m4 = fminf(G##4, b11), m5 = fminf(G##5, b10);       \
    float m6 = fminf(G##6, b9),  m7 = fminf(G##7, b8);        \
    float m8 = fminf(G##8, b7),  m9 = fminf(G##9, b6);        \
    float m10 = fminf(G##10, b5), m11 = fminf(G##11, b4);     \
    float m12 = b3, m13 = b2, m14 = b1, m15 = b0;             \
    CLEAN16();                                                \
    G##0 = m0; G##1 = m1; G##2 = m2; G##3 = m3;               \
    G##4 = m4; G##5 = m5; G##6 = m6; G##7 = m7;               \
    G##8 = m8; G##9 = m9; G##10 = m10; G##11 = m11; }

#define MERGE8(mask) {                                   \
    float b0 = __shfl_xor(d0, (mask), 64);               \
    float b1 = __shfl_xor(d1, (mask), 64);               \
    float b2 = __shfl_xor(d2, (mask), 64);               \
    float b3 = __shfl_xor(d3, (mask), 64);               \
    float b4 = __shfl_xor(d4, (mask), 64);               \
    float b5 = __shfl_xor(d5, (mask), 64);               \
    float b6 = __shfl_xor(d6, (mask), 64);               \
    float b7 = __shfl_xor(d7, (mask), 64);               \
    float m0 = fminf(d0, b7), m1 = fminf(d1, b6);        \
    float m2 = fminf(d2, b5), m3 = fminf(d3, b4);        \
    float m4 = fminf(d4, b3), m5 = fminf(d5, b2);        \
    float m6 = fminf(d6, b1), m7 = fminf(d7, b0);        \
    CSW(0,4) CSW(1,5) CSW(2,6) CSW(3,7)                  \
    CSW(0,2) CSW(1,3) CSW(4,6) CSW(5,7)                  \
    CSW(0,1) CSW(2,3) CSW(4,5) CSW(6,7)                  \
    d0 = m0; d1 = m1; d2 = m2; d3 = m3;                  \
    d4 = m4; d5 = m5; d6 = m6; d7 = m7; }

// ---- K1: encoder MLP -> x, H/L/YH/YL f16 splits, SQF, ACC ----
// (round-7 encoder minus the now-unused SQHL output)
__global__ __launch_bounds__(64) void k_encoder(
    const float* __restrict__ x_pfc,
    const float* __restrict__ W1, const float* __restrict__ b1,
    const float* __restrict__ W2, const float* __restrict__ b2,
    const float* __restrict__ W3, const float* __restrict__ b3,
    const float* __restrict__ We, const float* __restrict__ be,
    float* __restrict__ xo, _Float16* __restrict__ H, _Float16* __restrict__ L,
    _Float16* __restrict__ YH, _Float16* __restrict__ YL,
    float* __restrict__ SQF, float* __restrict__ ACC)
{
    __shared__ float sW1[DIN * 8];
    __shared__ float sb1[8];
    __shared__ float sW2[8 * 16];
    __shared__ float sb2[16];
    __shared__ float sW3[16 * 15];
    __shared__ float sb3[15];
    __shared__ float sWe[16 * 16];
    __shared__ float sbe[16];
    int t = threadIdx.x;
    for (int q = t; q < DIN * 8; q += 64) sW1[q] = W1[q];
    for (int q = t; q < 8; q += 64) sb1[q] = b1[q];
    for (int q = t; q < 8 * 16; q += 64) sW2[q] = W2[q];
    for (int q = t; q < 16; q += 64) sb2[q] = b2[q];
    for (int q = t; q < 16 * 15; q += 64) sW3[q] = W3[q];
    for (int q = t; q < 15; q += 64) sb3[q] = b3[q];
    for (int q = t; q < 16 * 16; q += 64) sWe[q] = We[q];
    for (int q = t; q < 16; q += 64) sbe[q] = be[q];
    __syncthreads();

    int i = blockIdx.x * 64 + t;
    float in[DIN];
#pragma unroll
    for (int d = 0; d < DIN; ++d) in[d] = x_pfc[i * DIN + d];

    float a1[8];
#pragma unroll
    for (int h = 0; h < 8; ++h) a1[h] = sb1[h];
#pragma unroll
    for (int d = 0; d < DIN; ++d) {
        float v = in[d];
#pragma unroll
        for (int h = 0; h < 8; ++h) a1[h] += v * sW1[d * 8 + h];
    }
#pragma unroll
    for (int h = 0; h < 8; ++h) a1[h] = silu(a1[h]);

    float a2[16];
#pragma unroll
    for (int h = 0; h < 16; ++h) a2[h] = sb2[h];
#pragma unroll
    for (int d = 0; d < 8; ++d) {
        float v = a1[d];
#pragma unroll
        for (int h = 0; h < 16; ++h) a2[h] += v * sW2[d * 16 + h];
    }
#pragma unroll
    for (int h = 0; h < 16; ++h) a2[h] = silu(a2[h]);

    float a3[15];
#pragma unroll
    for (int h = 0; h < 15; ++h) a3[h] = sb3[h];
#pragma unroll
    for (int d = 0; d < 16; ++d) {
        float v = a2[d];
#pragma unroll
        for (int h = 0; h < 15; ++h) a3[h] += v * sW3[d * 15 + h];
    }

    float xr[16];
#pragma unroll
    for (int h = 0; h < 15; ++h) xr[h] = a3[h];
    xr[15] = in[DIN - 1];

    float s = 0.0f;
#pragma unroll
    for (int d = 0; d < 16; ++d) s += xr[d] * xr[d];

    float accb[16];
#pragma unroll
    for (int h = 0; h < 16; ++h) accb[h] = sbe[h];
#pragma unroll
    for (int d = 0; d < 16; ++d) {
        float v = xr[d];
#pragma unroll
        for (int h = 0; h < 16; ++h) accb[h] += v * sWe[d * 16 + h];
    }

    _Float16 hb[16], lb[16], yhb[16], ylb[16];
#pragma unroll
    for (int d = 0; d < 16; ++d) {
        _Float16 h = (_Float16)xr[d];
        hb[d] = h;
        lb[d] = (_Float16)(xr[d] - (float)h);
        float y = -2.0f * xr[d];
        _Float16 yh = (_Float16)y;
        yhb[d] = yh;
        ylb[d] = (_Float16)(y - (float)yh);
    }
    {
        uint4* p;
        p = (uint4*)(H + (size_t)i * 16);  p[0] = ((uint4*)hb)[0];  p[1] = ((uint4*)hb)[1];
        p = (uint4*)(L + (size_t)i * 16);  p[0] = ((uint4*)lb)[0];  p[1] = ((uint4*)lb)[1];
        p = (uint4*)(YH + (size_t)i * 16); p[0] = ((uint4*)yhb)[0]; p[1] = ((uint4*)yhb)[1];
        p = (uint4*)(YL + (size_t)i * 16); p[0] = ((uint4*)ylb)[0]; p[1] = ((uint4*)ylb)[1];
        f32x4* xq = (f32x4*)(xo + (size_t)i * 16);
        f32x4* aq = (f32x4*)(ACC + (size_t)i * 16);
#pragma unroll
        for (int q = 0; q < 4; ++q) {
            f32x4 xv, av;
#pragma unroll
            for (int r = 0; r < 4; ++r) { xv[r] = xr[q * 4 + r]; av[r] = accb[q * 4 + r]; }
            xq[q] = xv;
            aq[q] = av;
        }
    }
    SQF[i] = s;
}

// ---- K2: fused knn + head (block-local handoff, NO cooperative launch) ----
// Round-21: round-20's cooperative launch silently no-op'd under graph
// capture (output = memset). Legal fusion without grid.sync: each block
// sweeps the FULL j-range (64 tiles/wave) for its own 64 i-points, so the
// knn->head dependency is block-local. Removes 1 dispatch boundary, the
// CV global round-trip (~3MB), and head's CV-merge preamble.
// id encoding: 10 bits = (tt<<4)|(w<<1)|hh, tt 0..63;
//   j-group base = w*2048 + tt*32 + hh*4 (+ ql*8 + qd members).
// LDS: 64KB sq/merge union + 3KB sList = 67KB -> 2 blocks/CU.
__global__ __launch_bounds__(512, 4) void k_knn_head(
    const _Float16* __restrict__ H, const _Float16* __restrict__ L,
    const _Float16* __restrict__ YH, const _Float16* __restrict__ YL,
    const float* __restrict__ SQF, const float* __restrict__ x,
    const float* __restrict__ x_pfc, const float* __restrict__ ACC,
    const float* __restrict__ We,
    const float* __restrict__ Wf1, const float* __restrict__ bf1,
    const float* __restrict__ Wf2, const float* __restrict__ bf2,
    float* __restrict__ out)
{
    __shared__ union SU {
        float knn[16384];                      // 64KB: full sq stage + merge tree
        struct {
            float we2[256]; float wf1[512]; float bf1s[32];
            float wf2[512]; float bf2s[16];
            int cnt[64]; int idx[64 * 8];
            float f1[32 * 33];
        } h;
    } S;
    __shared__ unsigned sList[64 * GL];        // survives phase transition (3KB)

    int t = threadIdx.x;
    int w = t >> 6;
    int lane = t & 63;
    int r31 = lane & 31;
    int hh = lane >> 5;
    int i0 = blockIdx.x * 64;

    // ================= Phase K: full-j MFMA sweep =================
    {
        int giA = i0 + r31;
        int giB = i0 + 32 + r31;
        half8 B1A = *(const half8*)(YH + (size_t)giA * 16 + hh * 8);
        half8 B2A = *(const half8*)(YL + (size_t)giA * 16 + hh * 8);
        half8 B1B = *(const half8*)(YH + (size_t)giB * 16 + hh * 8);
        half8 B2B = *(const half8*)(YL + (size_t)giB * 16 + hh * 8);

        // stage ALL of SQF (16384 f32 = 4096 f32x4), coalesced
        {
            const f32x4* src = (const f32x4*)SQF;
            f32x4* dst = (f32x4*)S.knn;
            for (int q = t; q < 4096; q += 512) dst[q] = src[q];
        }

        float gA0 = BIGF, gA1 = BIGF, gA2 = BIGF, gA3 = BIGF;
        float gA4 = BIGF, gA5 = BIGF, gA6 = BIGF, gA7 = BIGF;
        float gA8 = BIGF, gA9 = BIGF, gA10 = BIGF, gA11 = BIGF;
        float gB0 = BIGF, gB1 = BIGF, gB2 = BIGF, gB3 = BIGF;
        float gB4 = BIGF, gB5 = BIGF, gB6 = BIGF, gB7 = BIGF;
        float gB8 = BIGF, gB9 = BIGF, gB10 = BIGF, gB11 = BIGF;

        // wave w sweeps j-window [w*2048, (w+1)*2048): 64 tiles of 32
        const _Float16* pH = H + ((size_t)(w * 2048 + r31)) * 16 + hh * 8;
        const _Float16* pL = L + ((size_t)(w * 2048 + r31)) * 16 + hh * 8;
        const float* sqb = S.knn + w * 2048 + hh * 4;
        unsigned idt = (unsigned)((w << 1) | hh);

        __syncthreads();   // sq staged

#pragma unroll 2
        for (int tt = 0; tt < 64; ++tt) {
            half8 Ah = *(const half8*)(pH + (size_t)tt * 512);
            half8 Al = *(const half8*)(pL + (size_t)tt * 512);
            const f32x4* s_ = (const f32x4*)(sqb + tt * 32);
            f32x4 s0 = s_[0], s1 = s_[2], s2 = s_[4], s3 = s_[6];

            C16 cA, cB;
            cA.q[0] = s0; cA.q[1] = s1; cA.q[2] = s2; cA.q[3] = s3;
            cB.q[0] = s0; cB.q[1] = s1; cB.q[2] = s2; cB.q[3] = s3;
            cA.w = __builtin_amdgcn_mfma_f32_32x32x16_f16(Ah, B1A, cA.w, 0, 0, 0);
            cB.w = __builtin_amdgcn_mfma_f32_32x32x16_f16(Ah, B1B, cB.w, 0, 0, 0);
            cA.w = __builtin_amdgcn_mfma_f32_32x32x16_f16(Al, B1A, cA.w, 0, 0, 0);
            cB.w = __builtin_amdgcn_mfma_f32_32x32x16_f16(Al, B1B, cB.w, 0, 0, 0);
            cA.w = __builtin_amdgcn_mfma_f32_32x32x16_f16(Ah, B2A, cA.w, 0, 0, 0);
            cB.w = __builtin_amdgcn_mfma_f32_32x32x16_f16(Ah, B2B, cB.w, 0, 0, 0);

            unsigned idc = idt + (unsigned)(tt << 4);
            {
                float v0 = fminf(fminf(cA.w[0], cA.w[1]), cA.w[2]);
                float v1 = fminf(fminf(cA.w[3], cA.w[4]), cA.w[5]);
                float v2 = fminf(fminf(cA.w[6], cA.w[7]), cA.w[8]);
                float v3 = fminf(fminf(cA.w[9], cA.w[10]), cA.w[11]);
                float v4 = fminf(fminf(cA.w[12], cA.w[13]), cA.w[14]);
                float v5 = fminf(fminf(v0, v1), cA.w[15]);
                float v6 = fminf(fminf(v2, v3), v4);
                float vmin = fminf(v5, v6);
                unsigned pk = (__float_as_uint(vmin) & 0xFFFFFC00u) | idc;
                float pf = __uint_as_float(pk);
                INS12L(gA, pf);
            }
            {
                float v0 = fminf(fminf(cB.w[0], cB.w[1]), cB.w[2]);
                float v1 = fminf(fminf(cB.w[3], cB.w[4]), cB.w[5]);
                float v2 = fminf(fminf(cB.w[6], cB.w[7]), cB.w[8]);
                float v3 = fminf(fminf(cB.w[9], cB.w[10]), cB.w[11]);
                float v4 = fminf(fminf(cB.w[12], cB.w[13]), cB.w[14]);
                float v5 = fminf(fminf(v0, v1), cB.w[15]);
                float v6 = fminf(fminf(v2, v3), v4);
                float vmin = fminf(v5, v6);
                unsigned pk = (__float_as_uint(vmin) & 0xFFFFFC00u) | idc;
                float pf = __uint_as_float(pk);
                INS12L(gB, pf);
            }
        }

        MERGE12_SHFLG(gA, 32);
        MERGE12_SHFLG(gB, 32);

        __syncthreads();   // sq reads done; S.knn reusable as merge tree

#define STORE24() if (lane < 32) {                           \
            S.knn[(w * 24 + 0) * 32 + r31] = gA0;            \
            S.knn[(w * 24 + 1) * 32 + r31] = gA1;            \
            S.knn[(w * 24 + 2) * 32 + r31] = gA2;            \
            S.knn[(w * 24 + 3) * 32 + r31] = gA3;            \
            S.knn[(w * 24 + 4) * 32 + r31] = gA4;            \
            S.knn[(w * 24 + 5) * 32 + r31] = gA5;            \
            S.knn[(w * 24 + 6) * 32 + r31] = gA6;            \
            S.knn[(w * 24 + 7) * 32 + r31] = gA7;            \
            S.knn[(w * 24 + 8) * 32 + r31] = gA8;            \
            S.knn[(w * 24 + 9) * 32 + r31] = gA9;            \
            S.knn[(w * 24 + 10) * 32 + r31] = gA10;          \
            S.knn[(w * 24 + 11) * 32 + r31] = gA11;          \
            S.knn[(w * 24 + 12) * 32 + r31] = gB0;           \
            S.knn[(w * 24 + 13) * 32 + r31] = gB1;           \
            S.knn[(w * 24 + 14) * 32 + r31] = gB2;           \
            S.knn[(w * 24 + 15) * 32 + r31] = gB3;           \
            S.knn[(w * 24 + 16) * 32 + r31] = gB4;           \
            S.knn[(w * 24 + 17) * 32 + r31] = gB5;           \
            S.knn[(w * 24 + 18) * 32 + r31] = gB6;           \
            S.knn[(w * 24 + 19) * 32 + r31] = gB7;           \
            S.knn[(w * 24 + 20) * 32 + r31] = gB8;           \
            S.knn[(w * 24 + 21) * 32 + r31] = gB9;           \
            S.knn[(w * 24 + 22) * 32 + r31] = gB10;          \
            S.knn[(w * 24 + 23) * 32 + r31] = gB11; }

        if (w >= 4) STORE24();
        __syncthreads();
        if (w < 4) {
            int pw = w + 4;
#define LDA(s) S.knn[(pw * 24 + (s)) * 32 + r31]
#define LDB(s) S.knn[(pw * 24 + 12 + (s)) * 32 + r31]
            MERGE12_LDSG(gA, LDA);
            MERGE12_LDSG(gB, LDB);
#undef LDA
#undef LDB
        }
        __syncthreads();
        if (w == 2 || w == 3) STORE24();
        __syncthreads();
        if (w < 2) {
            int pw = w + 2;
#define LDA(s) S.knn[(pw * 24 + (s)) * 32 + r31]
#define LDB(s) S.knn[(pw * 24 + 12 + (s)) * 32 + r31]
            MERGE12_LDSG(gA, LDA);
            MERGE12_LDSG(gB, LDB);
#undef LDA
#undef LDB
        }
        __syncthreads();
        if (w == 1) STORE24();
        __syncthreads();
        if (w == 0) {
            int pw = 1;
#define LDA(s) S.knn[(pw * 24 + (s)) * 32 + r31]
#define LDB(s) S.knn[(pw * 24 + 12 + (s)) * 32 + r31]
            MERGE12_LDSG(gA, LDA);
            MERGE12_LDSG(gB, LDB);
#undef LDA
#undef LDB
            if (lane < 32) {
                // final top-12 lists -> LDS (replaces CV global round-trip)
                sList[r31 * GL + 0] = __float_as_uint(gA0);
                sList[r31 * GL + 1] = __float_as_uint(gA1);
                sList[r31 * GL + 2] = __float_as_uint(gA2);
                sList[r31 * GL + 3] = __float_as_uint(gA3);
                sList[r31 * GL + 4] = __float_as_uint(gA4);
                sList[r31 * GL + 5] = __float_as_uint(gA5);
                sList[r31 * GL + 6] = __float_as_uint(gA6);
                sList[r31 * GL + 7] = __float_as_uint(gA7);
                sList[r31 * GL + 8] = __float_as_uint(gA8);
                sList[r31 * GL + 9] = __float_as_uint(gA9);
                sList[r31 * GL + 10] = __float_as_uint(gA10);
                sList[r31 * GL + 11] = __float_as_uint(gA11);
                sList[(32 + r31) * GL + 0] = __float_as_uint(gB0);
                sList[(32 + r31) * GL + 1] = __float_as_uint(gB1);
                sList[(32 + r31) * GL + 2] = __float_as_uint(gB2);
                sList[(32 + r31) * GL + 3] = __float_as_uint(gB3);
                sList[(32 + r31) * GL + 4] = __float_as_uint(gB4);
                sList[(32 + r31) * GL + 5] = __float_as_uint(gB5);
                sList[(32 + r31) * GL + 6] = __float_as_uint(gB6);
                sList[(32 + r31) * GL + 7] = __float_as_uint(gB7);
                sList[(32 + r31) * GL + 8] = __float_as_uint(gB8);
                sList[(32 + r31) * GL + 9] = __float_as_uint(gB9);
                sList[(32 + r31) * GL + 10] = __float_as_uint(gB10);
                sList[(32 + r31) * GL + 11] = __float_as_uint(gB11);
            }
        }
#undef STORE24
    }

    __syncthreads();   // lists final; S.knn free for head weights

    // ================= Phase H: head (2 passes x 32 points) =================
    {
        for (int q = t; q < 16 * 16; q += 512) S.h.we2[q] = We[256 + q];
        for (int q = t; q < 16 * 32; q += 512) S.h.wf1[q] = Wf1[q];
        for (int q = t; q < 32; q += 512) S.h.bf1s[q] = bf1[q];
        for (int q = t; q < 32 * 16; q += 512) S.h.wf2[q] = Wf2[q];
        for (int q = t; q < 16; q += 512) S.h.bf2s[q] = bf2[q];
        if (t < 64) S.h.cnt[t] = 0;
        __syncthreads();

        int l = t & 15;          // lane within point
        int ptl = t >> 4;        // point-slot within pass (0..31)
        int ql = l & 3;
        int qd = l >> 2;

#pragma unroll 1
        for (int pass = 0; pass < 2; ++pass) {
            int pt = pass * 32 + ptl;    // 0..63
            int i = i0 + pt;

            float xi[16];
            {
                const f32x4* xiv = (const f32x4*)(x + (size_t)i * 16);
#pragma unroll
                for (int q = 0; q < 4; ++q) {
                    f32x4 a = xiv[q];
#pragma unroll
                    for (int r = 0; r < 4; ++r) xi[q * 4 + r] = a[r];
                }
            }
            f32x4 xiq = ((const f32x4*)(x + (size_t)i * 16))[ql];

            // scan A: 12 groups x 4 coalesced runs
            float val[12];
            int jbs[12];
            float d0 = BIGF, d1 = BIGF, d2 = BIGF, d3 = BIGF;
            float d4 = BIGF, d5 = BIGF, d6 = BIGF, d7 = BIGF;
#pragma unroll
            for (int g = 0; g < GL; ++g) {
                unsigned id = sList[pt * GL + g] & 0x3FFu;
                int jb = (int)(((id >> 1) & 7) * 2048 + (id >> 4) * 32 + (id & 1) * 4);
                jbs[g] = jb;
                float vg = BIGF;
#pragma unroll
                for (int rho = 0; rho < 4; ++rho) {
                    f32x4 a = *((const f32x4*)(x + ((size_t)(jb + rho * 8)) * 16) + l);
                    float qdot = xiq[0] * a[0];
                    qdot = fmaf(xiq[1], a[1], qdot);
                    qdot = fmaf(xiq[2], a[2], qdot);
                    qdot = fmaf(xiq[3], a[3], qdot);
                    qdot += __shfl_xor(qdot, 1, 64);
                    qdot += __shfl_xor(qdot, 2, 64);
                    float v = fmaf(qdot, -2.0f, SQF[jb + rho * 8 + qd]);
                    vg = (ql == rho) ? v : vg;
                }
                val[g] = vg;
                INS8V(vg);
            }

            // exact kth over the point's 192 candidates (16-lane butterfly)
            MERGE8(1);
            MERGE8(2);
            MERGE8(4);
            MERGE8(8);
            float kth = d7;

            // scan B: register re-scan, collect ids
#pragma unroll
            for (int g = 0; g < GL; ++g) {
                float v = val[g];
                if (v <= kth) {
                    int j = jbs[g] + ql * 8 + qd;
                    int p = atomicAdd(&S.h.cnt[pt], 1);
                    if (p < KNN) S.h.idx[pt * 8 + p] = j;
                }
            }
            __syncthreads();

            int e8 = l & 7;
            int j = S.h.idx[pt * 8 + e8];

            float xd[16];
            {
                const f32x4* xjv = (const f32x4*)(x + (size_t)j * 16);
#pragma unroll
                for (int q = 0; q < 4; ++q) {
                    f32x4 a = xjv[q];
#pragma unroll
                    for (int r = 0; r < 4; ++r) xd[q * 4 + r] = a[r] - xi[q * 4 + r];
                }
            }

            float acc[16];
            {
                const f32x4* av = (const f32x4*)(ACC + (size_t)i * 16);
#pragma unroll
                for (int q = 0; q < 4; ++q) {
                    f32x4 a = av[q];
#pragma unroll
                    for (int r = 0; r < 4; ++r) acc[q * 4 + r] = a[r];
                }
            }
#pragma unroll
            for (int d = 0; d < 16; ++d) {
                float v = xd[d];
#pragma unroll
                for (int h = 0; h < 16; ++h) acc[h] += v * S.h.we2[d * 16 + h];
            }

            float feats[16];
#pragma unroll
            for (int h = 0; h < 16; ++h) feats[h] = silu(acc[h]);

#pragma unroll
            for (int mask = 1; mask <= 4; mask <<= 1) {
#pragma unroll
                for (int h = 0; h < 16; ++h) feats[h] += __shfl_xor(feats[h], mask, 64);
            }
#pragma unroll
            for (int h = 0; h < 16; ++h) feats[h] *= 0.125f;

            // f1: lane l computes outputs l and l+16
            float p0 = S.h.bf1s[l];
            float p1 = S.h.bf1s[l + 16];
#pragma unroll
            for (int k = 0; k < 16; ++k) {
                float v = feats[k];
                p0 = fmaf(v, S.h.wf1[k * 32 + l], p0);
                p1 = fmaf(v, S.h.wf1[k * 32 + l + 16], p1);
            }
            p0 = silu(p0);
            p1 = silu(p1);
            S.h.f1[ptl * 33 + l] = p0;
            S.h.f1[ptl * 33 + 16 + l] = p1;
            __syncthreads();

            // f2: lane l computes output l
            float o = S.h.bf2s[l];
#pragma unroll
            for (int k = 0; k < 32; ++k)
                o = fmaf(S.h.f1[ptl * 33 + k], S.h.wf2[k * 16 + l], o);

            out[(size_t)i * 29 + l] = o;
            if (l < DIN) out[(size_t)i * 29 + 16 + l] = x_pfc[i * DIN + l];
            __syncthreads();   // f1 region reused by next pass
        }
    }
}

extern "C" void kernel_launch(void* const* d_in, const int* in_sizes, int n_in,
                              void* d_out, int out_size, void* d_ws, size_t ws_size,
                              hipStream_t stream)
{
    const float* x_pfc = (const float*)d_in[0];
    const float* W1 = (const float*)d_in[1];
    const float* b1 = (const float*)d_in[2];
    const float* W2 = (const float*)d_in[3];
    const float* b2 = (const float*)d_in[4];
    const float* W3 = (const float*)d_in[5];
    const float* b3 = (const float*)d_in[6];
    const float* We = (const float*)d_in[7];
    const float* be = (const float*)d_in[8];
    const float* Wf1 = (const float*)d_in[9];
    const float* bf1 = (const float*)d_in[10];
    const float* Wf2 = (const float*)d_in[11];
    const float* bf2 = (const float*)d_in[12];
    float* out = (float*)d_out;

    float* xw = (float*)d_ws;                         // N*16 f32
    float* ACCa = xw + (size_t)NPTS * 16;             // N*16 f32
    _Float16* Ha = (_Float16*)(ACCa + (size_t)NPTS * 16);  // N*16 f16
    _Float16* La = Ha + (size_t)NPTS * 16;
    _Float16* YHa = La + (size_t)NPTS * 16;
    _Float16* YLa = YHa + (size_t)NPTS * 16;
    float* SQFa = (float*)(YLa + (size_t)NPTS * 16);  // N f32

    hipLaunchKernelGGL(k_encoder, dim3(NPTS / 64), dim3(64), 0, stream,
                       x_pfc, W1, b1, W2, b2, W3, b3, We, be,
                       xw, Ha, La, YHa, YLa, SQFa, ACCa);
    hipLaunchKernelGGL(k_knn_head, dim3(NPTS / 64), dim3(512), 0, stream,
                       Ha, La, YHa, YLa, SQFa, xw, x_pfc, ACCa,
                       We, Wf1, bf1, Wf2, bf2, out);
}

// Round 10
// 136.971 us; speedup vs baseline: 1.1164x; 1.0193x over previous
//
#include <hip/hip_runtime.h>
#include <math.h>

#define NPTS 16384
#define DIN 13
#define KNN 8
#define GL 12                 // group-list depth
#define BIGF 1.7014118e38f    // 0x7F000000 — finite sentinel, id bits 0

typedef _Float16 half8 __attribute__((ext_vector_type(8)));
typedef float f32x4 __attribute__((ext_vector_type(4)));
typedef float f32x16 __attribute__((ext_vector_type(16)));

union C16 { f32x16 w; f32x4 q[4]; };

__device__ __forceinline__ float silu(float v) {
    return v / (1.0f + __expf(-v));
}

#define MED3(v, a, b) __builtin_amdgcn_fmed3f((v), (a), (b))

#define INS8V(v) {                      \
    d7 = MED3((v), d6, d7);             \
    d6 = MED3((v), d5, d6);             \
    d5 = MED3((v), d4, d5);             \
    d4 = MED3((v), d3, d4);             \
    d3 = MED3((v), d2, d3);             \
    d2 = MED3((v), d1, d2);             \
    d1 = MED3((v), d0, d1);             \
    d0 = fminf((v), d0); }

// 12-deep sorted-insert (g0..g11)
#define INS12G(v) {                     \
    g11 = MED3((v), g10, g11);          \
    g10 = MED3((v), g9, g10);           \
    g9  = MED3((v), g8, g9);            \
    g8  = MED3((v), g7, g8);            \
    g7  = MED3((v), g6, g7);            \
    g6  = MED3((v), g5, g6);            \
    g5  = MED3((v), g4, g5);            \
    g4  = MED3((v), g3, g4);            \
    g3  = MED3((v), g2, g3);            \
    g2  = MED3((v), g1, g2);            \
    g1  = MED3((v), g0, g1);            \
    g0  = fminf((v), g0); }

#define CSW(p, q) { float lo_ = fminf(m##p, m##q); float hi_ = fmaxf(m##p, m##q); m##p = lo_; m##q = hi_; }

#define CLEAN16() \
    CSW(0,8) CSW(1,9) CSW(2,10) CSW(3,11) CSW(4,12) CSW(5,13) CSW(6,14) CSW(7,15) \
    CSW(0,4) CSW(1,5) CSW(2,6) CSW(3,7) CSW(8,12) CSW(9,13) CSW(10,14) CSW(11,15) \
    CSW(0,2) CSW(1,3) CSW(4,6) CSW(5,7) CSW(8,10) CSW(9,11) CSW(12,14) CSW(13,15) \
    CSW(0,1) CSW(2,3) CSW(4,5) CSW(6,7) CSW(8,9) CSW(10,11) CSW(12,13) CSW(14,15)

#define MERGE12_SHFL(mask) {                                  \
    float b0 = __shfl_xor(g0, (mask), 64);                    \
    float b1 = __shfl_xor(g1, (mask), 64);                    \
    float b2 = __shfl_xor(g2, (mask), 64);                    \
    float b3 = __shfl_xor(g3, (mask), 64);                    \
    float b4 = __shfl_xor(g4, (mask), 64);                    \
    float b5 = __shfl_xor(g5, (mask), 64);                    \
    float b6 = __shfl_xor(g6, (mask), 64);                    \
    float b7 = __shfl_xor(g7, (mask), 64);                    \
    float b8 = __shfl_xor(g8, (mask), 64);                    \
    float b9 = __shfl_xor(g9, (mask), 64);                    \
    float b10 = __shfl_xor(g10, (mask), 64);                  \
    float b11 = __shfl_xor(g11, (mask), 64);                  \
    float m0 = g0, m1 = g1, m2 = g2, m3 = g3;                 \
    float m4 = fminf(g4, b11), m5 = fminf(g5, b10);           \
    float m6 = fminf(g6, b9),  m7 = fminf(g7, b8);            \
    float m8 = fminf(g8, b7),  m9 = fminf(g9, b6);            \
    float m10 = fminf(g10, b5), m11 = fminf(g11, b4);         \
    float m12 = b3, m13 = b2, m14 = b1, m15 = b0;             \
    CLEAN16();                                                \
    g0 = m0; g1 = m1; g2 = m2; g3 = m3; g4 = m4; g5 = m5;     \
    g6 = m6; g7 = m7; g8 = m8; g9 = m9; g10 = m10; g11 = m11; }

#define MERGE12_LDS(LD) {                                     \
    float b0 = LD(0), b1 = LD(1), b2 = LD(2), b3 = LD(3);     \
    float b4 = LD(4), b5 = LD(5), b6 = LD(6), b7 = LD(7);     \
    float b8 = LD(8), b9 = LD(9), b10 = LD(10), b11 = LD(11); \
    float m0 = g0, m1 = g1, m2 = g2, m3 = g3;                 \
    float m4 = fminf(g4, b11), m5 = fminf(g5, b10);           \
    float m6 = fminf(g6, b9),  m7 = fminf(g7, b8);            \
    float m8 = fminf(g8, b7),  m9 = fminf(g9, b6);            \
    float m10 = fminf(g10, b5), m11 = fminf(g11, b4);         \
    float m12 = b3, m13 = b2, m14 = b1, m15 = b0;             \
    CLEAN16();                                                \
    g0 = m0; g1 = m1; g2 = m2; g3 = m3; g4 = m4; g5 = m5;     \
    g6 = m6; g7 = m7; g8 = m8; g9 = m9; g10 = m10; g11 = m11; }

#define MERGE8(mask) {                                   \
    float b0 = __shfl_xor(d0, (mask), 64);               \
    float b1 = __shfl_xor(d1, (mask), 64);               \
    float b2 = __shfl_xor(d2, (mask), 64);               \
    float b3 = __shfl_xor(d3, (mask), 64);               \
    float b4 = __shfl_xor(d4, (mask), 64);               \
    float b5 = __shfl_xor(d5, (mask), 64);               \
    float b6 = __shfl_xor(d6, (mask), 64);               \
    float b7 = __shfl_xor(d7, (mask), 64);               \
    float m0 = fminf(d0, b7), m1 = fminf(d1, b6);        \
    float m2 = fminf(d2, b5), m3 = fminf(d3, b4);        \
    float m4 = fminf(d4, b3), m5 = fminf(d5, b2);        \
    float m6 = fminf(d6, b1), m7 = fminf(d7, b0);        \
    CSW(0,4) CSW(1,5) CSW(2,6) CSW(3,7)                  \
    CSW(0,2) CSW(1,3) CSW(4,6) CSW(5,7)                  \
    CSW(0,1) CSW(2,3) CSW(4,5) CSW(6,7)                  \
    d0 = m0; d1 = m1; d2 = m2; d3 = m3;                  \
    d4 = m4; d5 = m5; d6 = m6; d7 = m7; }

// ---- K1: encoder MLP -> x, H/L/YH/YL f16 splits, SQF, ACC ----
__global__ __launch_bounds__(64) void k_encoder(
    const float* __restrict__ x_pfc,
    const float* __restrict__ W1, const float* __restrict__ b1,
    const float* __restrict__ W2, const float* __restrict__ b2,
    const float* __restrict__ W3, const float* __restrict__ b3,
    const float* __restrict__ We, const float* __restrict__ be,
    float* __restrict__ xo, _Float16* __restrict__ H, _Float16* __restrict__ L,
    _Float16* __restrict__ YH, _Float16* __restrict__ YL,
    float* __restrict__ SQF, float* __restrict__ ACC)
{
    __shared__ float sW1[DIN * 8];
    __shared__ float sb1[8];
    __shared__ float sW2[8 * 16];
    __shared__ float sb2[16];
    __shared__ float sW3[16 * 15];
    __shared__ float sb3[15];
    __shared__ float sWe[16 * 16];
    __shared__ float sbe[16];
    int t = threadIdx.x;
    for (int q = t; q < DIN * 8; q += 64) sW1[q] = W1[q];
    for (int q = t; q < 8; q += 64) sb1[q] = b1[q];
    for (int q = t; q < 8 * 16; q += 64) sW2[q] = W2[q];
    for (int q = t; q < 16; q += 64) sb2[q] = b2[q];
    for (int q = t; q < 16 * 15; q += 64) sW3[q] = W3[q];
    for (int q = t; q < 15; q += 64) sb3[q] = b3[q];
    for (int q = t; q < 16 * 16; q += 64) sWe[q] = We[q];
    for (int q = t; q < 16; q += 64) sbe[q] = be[q];
    __syncthreads();

    int i = blockIdx.x * 64 + t;
    float in[DIN];
#pragma unroll
    for (int d = 0; d < DIN; ++d) in[d] = x_pfc[i * DIN + d];

    float a1[8];
#pragma unroll
    for (int h = 0; h < 8; ++h) a1[h] = sb1[h];
#pragma unroll
    for (int d = 0; d < DIN; ++d) {
        float v = in[d];
#pragma unroll
        for (int h = 0; h < 8; ++h) a1[h] += v * sW1[d * 8 + h];
    }
#pragma unroll
    for (int h = 0; h < 8; ++h) a1[h] = silu(a1[h]);

    float a2[16];
#pragma unroll
    for (int h = 0; h < 16; ++h) a2[h] = sb2[h];
#pragma unroll
    for (int d = 0; d < 8; ++d) {
        float v = a1[d];
#pragma unroll
        for (int h = 0; h < 16; ++h) a2[h] += v * sW2[d * 16 + h];
    }
#pragma unroll
    for (int h = 0; h < 16; ++h) a2[h] = silu(a2[h]);

    float a3[15];
#pragma unroll
    for (int h = 0; h < 15; ++h) a3[h] = sb3[h];
#pragma unroll
    for (int d = 0; d < 16; ++d) {
        float v = a2[d];
#pragma unroll
        for (int h = 0; h < 15; ++h) a3[h] += v * sW3[d * 15 + h];
    }

    float xr[16];
#pragma unroll
    for (int h = 0; h < 15; ++h) xr[h] = a3[h];
    xr[15] = in[DIN - 1];

    float s = 0.0f;
#pragma unroll
    for (int d = 0; d < 16; ++d) s += xr[d] * xr[d];

    float accb[16];
#pragma unroll
    for (int h = 0; h < 16; ++h) accb[h] = sbe[h];
#pragma unroll
    for (int d = 0; d < 16; ++d) {
        float v = xr[d];
#pragma unroll
        for (int h = 0; h < 16; ++h) accb[h] += v * sWe[d * 16 + h];
    }

    _Float16 hb[16], lb[16], yhb[16], ylb[16];
#pragma unroll
    for (int d = 0; d < 16; ++d) {
        _Float16 h = (_Float16)xr[d];
        hb[d] = h;
        lb[d] = (_Float16)(xr[d] - (float)h);
        float y = -2.0f * xr[d];
        _Float16 yh = (_Float16)y;
        yhb[d] = yh;
        ylb[d] = (_Float16)(y - (float)yh);
    }
    {
        uint4* p;
        p = (uint4*)(H + (size_t)i * 16);  p[0] = ((uint4*)hb)[0];  p[1] = ((uint4*)hb)[1];
        p = (uint4*)(L + (size_t)i * 16);  p[0] = ((uint4*)lb)[0];  p[1] = ((uint4*)lb)[1];
        p = (uint4*)(YH + (size_t)i * 16); p[0] = ((uint4*)yhb)[0]; p[1] = ((uint4*)yhb)[1];
        p = (uint4*)(YL + (size_t)i * 16); p[0] = ((uint4*)ylb)[0]; p[1] = ((uint4*)ylb)[1];
        f32x4* xq = (f32x4*)(xo + (size_t)i * 16);
        f32x4* aq = (f32x4*)(ACC + (size_t)i * 16);
#pragma unroll
        for (int q = 0; q < 4; ++q) {
            f32x4 xv, av;
#pragma unroll
            for (int r = 0; r < 4; ++r) { xv[r] = xr[q * 4 + r]; av[r] = accb[q * 4 + r]; }
            xq[q] = xv;
            aq[q] = av;
        }
    }
    SQF[i] = s;
}

// ---- K2: fused knn + head, 32 i-points/block, full-j sweep ----
// Round-22: round-21 fused correctly (total 150->139.6) but grid=256 on
// 256 CUs gave 1 block/CU = 2 waves/SIMD (Occupancy 20%, ~40% idle issue).
// Now grid=512 (32 i-pts/block): one B-set -> 3 MFMA/tile, single
// min-tree+INS12 chain (knn VALU/wave halves), single-pass head.
// LDS = 64KB sq + 1.5KB sList + aliased head region -> 2 blocks/CU
// = 4 waves/SIMD, and the two blocks' knn/head phases overlap.
// Cost: H/L L2 traffic doubles (~512MB, ~15us demand) — overlappable.
__global__ __launch_bounds__(512, 4) void k_knn_head(
    const _Float16* __restrict__ H, const _Float16* __restrict__ L,
    const _Float16* __restrict__ YH, const _Float16* __restrict__ YL,
    const float* __restrict__ SQF, const float* __restrict__ x,
    const float* __restrict__ x_pfc, const float* __restrict__ ACC,
    const float* __restrict__ We,
    const float* __restrict__ Wf1, const float* __restrict__ bf1,
    const float* __restrict__ Wf2, const float* __restrict__ bf2,
    float* __restrict__ out)
{
    __shared__ union SU {
        float knn[16384];                      // 64KB: full sq stage + merge tree
        struct {
            float we2[256]; float wf1[512]; float bf1s[32];
            float wf2[512]; float bf2s[16];
            int cnt[32]; int idx[256];
            float f1[32 * 33];
        } h;
    } S;
    __shared__ unsigned sList[32 * GL];        // survives phase transition (1.5KB)

    int t = threadIdx.x;
    int w = t >> 6;
    int lane = t & 63;
    int r31 = lane & 31;
    int hh = lane >> 5;
    int i0 = blockIdx.x * 32;

    // ================= Phase K: full-j MFMA sweep =================
    {
        int gi = i0 + r31;
        half8 B1 = *(const half8*)(YH + (size_t)gi * 16 + hh * 8);
        half8 B2 = *(const half8*)(YL + (size_t)gi * 16 + hh * 8);

        // stage ALL of SQF (16384 f32 = 4096 f32x4), coalesced
        {
            const f32x4* src = (const f32x4*)SQF;
            f32x4* dst = (f32x4*)S.knn;
            for (int q = t; q < 4096; q += 512) dst[q] = src[q];
        }

        float g0 = BIGF, g1 = BIGF, g2 = BIGF, g3 = BIGF;
        float g4 = BIGF, g5 = BIGF, g6 = BIGF, g7 = BIGF;
        float g8 = BIGF, g9 = BIGF, g10 = BIGF, g11 = BIGF;

        // wave w sweeps j-window [w*2048, (w+1)*2048): 64 tiles of 32
        const _Float16* pH = H + ((size_t)(w * 2048 + r31)) * 16 + hh * 8;
        const _Float16* pL = L + ((size_t)(w * 2048 + r31)) * 16 + hh * 8;
        const float* sqb = S.knn + w * 2048 + hh * 4;
        unsigned idt = (unsigned)((w << 1) | hh);

        __syncthreads();   // sq staged

#pragma unroll 2
        for (int tt = 0; tt < 64; ++tt) {
            half8 Ah = *(const half8*)(pH + (size_t)tt * 512);
            half8 Al = *(const half8*)(pL + (size_t)tt * 512);
            const f32x4* s_ = (const f32x4*)(sqb + tt * 32);

            C16 c;
            c.q[0] = s_[0]; c.q[1] = s_[2]; c.q[2] = s_[4]; c.q[3] = s_[6];
            c.w = __builtin_amdgcn_mfma_f32_32x32x16_f16(Ah, B1, c.w, 0, 0, 0);
            c.w = __builtin_amdgcn_mfma_f32_32x32x16_f16(Al, B1, c.w, 0, 0, 0);
            c.w = __builtin_amdgcn_mfma_f32_32x32x16_f16(Ah, B2, c.w, 0, 0, 0);

            float v0 = fminf(fminf(c.w[0], c.w[1]), c.w[2]);
            float v1 = fminf(fminf(c.w[3], c.w[4]), c.w[5]);
            float v2 = fminf(fminf(c.w[6], c.w[7]), c.w[8]);
            float v3 = fminf(fminf(c.w[9], c.w[10]), c.w[11]);
            float v4 = fminf(fminf(c.w[12], c.w[13]), c.w[14]);
            float v5 = fminf(fminf(v0, v1), c.w[15]);
            float v6 = fminf(fminf(v2, v3), v4);
            float vmin = fminf(v5, v6);

            unsigned pk = (__float_as_uint(vmin) & 0xFFFFFC00u)
                        | (idt + (unsigned)(tt << 4));
            float pf = __uint_as_float(pk);
            INS12G(pf);
        }

        MERGE12_SHFL(32);

        __syncthreads();   // sq reads done; S.knn reusable as merge tree

#define STORE12() if (lane < 32) {                           \
            S.knn[(w * GL + 0) * 32 + r31] = g0;             \
            S.knn[(w * GL + 1) * 32 + r31] = g1;             \
            S.knn[(w * GL + 2) * 32 + r31] = g2;             \
            S.knn[(w * GL + 3) * 32 + r31] = g3;             \
            S.knn[(w * GL + 4) * 32 + r31] = g4;             \
            S.knn[(w * GL + 5) * 32 + r31] = g5;             \
            S.knn[(w * GL + 6) * 32 + r31] = g6;             \
            S.knn[(w * GL + 7) * 32 + r31] = g7;             \
            S.knn[(w * GL + 8) * 32 + r31] = g8;             \
            S.knn[(w * GL + 9) * 32 + r31] = g9;             \
            S.knn[(w * GL + 10) * 32 + r31] = g10;           \
            S.knn[(w * GL + 11) * 32 + r31] = g11; }

        if (w >= 4) STORE12();
        __syncthreads();
        if (w < 4) {
            int pw = w + 4;
#define LD(s) S.knn[(pw * GL + (s)) * 32 + r31]
            MERGE12_LDS(LD);
#undef LD
        }
        __syncthreads();
        if (w == 2 || w == 3) STORE12();
        __syncthreads();
        if (w < 2) {
            int pw = w + 2;
#define LD(s) S.knn[(pw * GL + (s)) * 32 + r31]
            MERGE12_LDS(LD);
#undef LD
        }
        __syncthreads();
        if (w == 1) STORE12();
        __syncthreads();
        if (w == 0) {
            int pw = 1;
#define LD(s) S.knn[(pw * GL + (s)) * 32 + r31]
            MERGE12_LDS(LD);
#undef LD
            if (lane < 32) {
                // final top-12 lists -> LDS (no CV global round-trip)
                sList[r31 * GL + 0] = __float_as_uint(g0);
                sList[r31 * GL + 1] = __float_as_uint(g1);
                sList[r31 * GL + 2] = __float_as_uint(g2);
                sList[r31 * GL + 3] = __float_as_uint(g3);
                sList[r31 * GL + 4] = __float_as_uint(g4);
                sList[r31 * GL + 5] = __float_as_uint(g5);
                sList[r31 * GL + 6] = __float_as_uint(g6);
                sList[r31 * GL + 7] = __float_as_uint(g7);
                sList[r31 * GL + 8] = __float_as_uint(g8);
                sList[r31 * GL + 9] = __float_as_uint(g9);
                sList[r31 * GL + 10] = __float_as_uint(g10);
                sList[r31 * GL + 11] = __float_as_uint(g11);
            }
        }
#undef STORE12
    }

    __syncthreads();   // lists final; S.knn free for head weights

    // ================= Phase H: head (32 points, 16 lanes each) ==========
    {
        for (int q = t; q < 16 * 16; q += 512) S.h.we2[q] = We[256 + q];
        for (int q = t; q < 16 * 32; q += 512) S.h.wf1[q] = Wf1[q];
        for (int q = t; q < 32; q += 512) S.h.bf1s[q] = bf1[q];
        for (int q = t; q < 32 * 16; q += 512) S.h.wf2[q] = Wf2[q];
        for (int q = t; q < 16; q += 512) S.h.bf2s[q] = bf2[q];
        if (t < 32) S.h.cnt[t] = 0;
        __syncthreads();

        int l = t & 15;          // lane within point
        int pt = t >> 4;         // point within block (0..31)
        int ql = l & 3;
        int qd = l >> 2;
        int i = i0 + pt;

        float xi[16];
        {
            const f32x4* xiv = (const f32x4*)(x + (size_t)i * 16);
#pragma unroll
            for (int q = 0; q < 4; ++q) {
                f32x4 a = xiv[q];
#pragma unroll
                for (int r = 0; r < 4; ++r) xi[q * 4 + r] = a[r];
            }
        }
        f32x4 xiq = ((const f32x4*)(x + (size_t)i * 16))[ql];

        // scan A: 12 groups x 4 coalesced runs
        float val[12];
        int jbs[12];
        float d0 = BIGF, d1 = BIGF, d2 = BIGF, d3 = BIGF;
        float d4 = BIGF, d5 = BIGF, d6 = BIGF, d7 = BIGF;
#pragma unroll
        for (int g = 0; g < GL; ++g) {
            unsigned id = sList[pt * GL + g] & 0x3FFu;
            int jb = (int)(((id >> 1) & 7) * 2048 + (id >> 4) * 32 + (id & 1) * 4);
            jbs[g] = jb;
            float vg = BIGF;
#pragma unroll
            for (int rho = 0; rho < 4; ++rho) {
                f32x4 a = *((const f32x4*)(x + ((size_t)(jb + rho * 8)) * 16) + l);
                float qdot = xiq[0] * a[0];
                qdot = fmaf(xiq[1], a[1], qdot);
                qdot = fmaf(xiq[2], a[2], qdot);
                qdot = fmaf(xiq[3], a[3], qdot);
                qdot += __shfl_xor(qdot, 1, 64);
                qdot += __shfl_xor(qdot, 2, 64);
                float v = fmaf(qdot, -2.0f, SQF[jb + rho * 8 + qd]);
                vg = (ql == rho) ? v : vg;
            }
            val[g] = vg;
            INS8V(vg);
        }

        // exact kth over the point's 192 candidates (16-lane butterfly)
        MERGE8(1);
        MERGE8(2);
        MERGE8(4);
        MERGE8(8);
        float kth = d7;

        // scan B: register re-scan, collect ids
#pragma unroll
        for (int g = 0; g < GL; ++g) {
            float v = val[g];
            if (v <= kth) {
                int j = jbs[g] + ql * 8 + qd;
                int p = atomicAdd(&S.h.cnt[pt], 1);
                if (p < KNN) S.h.idx[pt * 8 + p] = j;
            }
        }
        __syncthreads();

        int e8 = l & 7;
        int j = S.h.idx[pt * 8 + e8];

        float xd[16];
        {
            const f32x4* xjv = (const f32x4*)(x + (size_t)j * 16);
#pragma unroll
            for (int q = 0; q < 4; ++q) {
                f32x4 a = xjv[q];
#pragma unroll
                for (int r = 0; r < 4; ++r) xd[q * 4 + r] = a[r] - xi[q * 4 + r];
            }
        }

        float acc[16];
        {
            const f32x4* av = (const f32x4*)(ACC + (size_t)i * 16);
#pragma unroll
            for (int q = 0; q < 4; ++q) {
                f32x4 a = av[q];
#pragma unroll
                for (int r = 0; r < 4; ++r) acc[q * 4 + r] = a[r];
            }
        }
#pragma unroll
        for (int d = 0; d < 16; ++d) {
            float v = xd[d];
#pragma unroll
            for (int h = 0; h < 16; ++h) acc[h] += v * S.h.we2[d * 16 + h];
        }

        float feats[16];
#pragma unroll
        for (int h = 0; h < 16; ++h) feats[h] = silu(acc[h]);

#pragma unroll
        for (int mask = 1; mask <= 4; mask <<= 1) {
#pragma unroll
            for (int h = 0; h < 16; ++h) feats[h] += __shfl_xor(feats[h], mask, 64);
        }
#pragma unroll
        for (int h = 0; h < 16; ++h) feats[h] *= 0.125f;

        // f1: lane l computes outputs l and l+16
        float p0 = S.h.bf1s[l];
        float p1 = S.h.bf1s[l + 16];
#pragma unroll
        for (int k = 0; k < 16; ++k) {
            float v = feats[k];
            p0 = fmaf(v, S.h.wf1[k * 32 + l], p0);
            p1 = fmaf(v, S.h.wf1[k * 32 + l + 16], p1);
        }
        p0 = silu(p0);
        p1 = silu(p1);
        S.h.f1[pt * 33 + l] = p0;
        S.h.f1[pt * 33 + 16 + l] = p1;
        __syncthreads();

        // f2: lane l computes output l
        float o = S.h.bf2s[l];
#pragma unroll
        for (int k = 0; k < 32; ++k)
            o = fmaf(S.h.f1[pt * 33 + k], S.h.wf2[k * 16 + l], o);

        out[(size_t)i * 29 + l] = o;
        if (l < DIN) out[(size_t)i * 29 + 16 + l] = x_pfc[i * DIN + l];
    }
}

extern "C" void kernel_launch(void* const* d_in, const int* in_sizes, int n_in,
                              void* d_out, int out_size, void* d_ws, size_t ws_size,
                              hipStream_t stream)
{
    const float* x_pfc = (const float*)d_in[0];
    const float* W1 = (const float*)d_in[1];
    const float* b1 = (const float*)d_in[2];
    const float* W2 = (const float*)d_in[3];
    const float* b2 = (const float*)d_in[4];
    const float* W3 = (const float*)d_in[5];
    const float* b3 = (const float*)d_in[6];
    const float* We = (const float*)d_in[7];
    const float* be = (const float*)d_in[8];
    const float* Wf1 = (const float*)d_in[9];
    const float* bf1 = (const float*)d_in[10];
    const float* Wf2 = (const float*)d_in[11];
    const float* bf2 = (const float*)d_in[12];
    float* out = (float*)d_out;

    float* xw = (float*)d_ws;                         // N*16 f32
    float* ACCa = xw + (size_t)NPTS * 16;             // N*16 f32
    _Float16* Ha = (_Float16*)(ACCa + (size_t)NPTS * 16);  // N*16 f16
    _Float16* La = Ha + (size_t)NPTS * 16;
    _Float16* YHa = La + (size_t)NPTS * 16;
    _Float16* YLa = YHa + (size_t)NPTS * 16;
    float* SQFa = (float*)(YLa + (size_t)NPTS * 16);  // N f32

    hipLaunchKernelGGL(k_encoder, dim3(NPTS / 64), dim3(64), 0, stream,
                       x_pfc, W1, b1, W2, b2, W3, b3, We, be,
                       xw, Ha, La, YHa, YLa, SQFa, ACCa);
    hipLaunchKernelGGL(k_knn_head, dim3(NPTS / 32), dim3(512), 0, stream,
                       Ha, La, YHa, YLa, SQFa, xw, x_pfc, ACCa,
                       We, Wf1, bf1, Wf2, bf2, out);
}